// Round 9
// baseline (5712.673 us; speedup 1.0000x reference)
//
#include <hip/hip_runtime.h>
#include <hip/hip_cooperative_groups.h>
#include <math.h>

// GIN: N=100000 nodes, E=1600000 edges, F=D=64, L=3 layers, C=10 classes.
// R9: persistent cooperative kernel kept, but cg::grid.sync() (poll-storm:
// 1.75GB of barrier traffic in R8) replaced by a single-use arrive-count
// barrier: only thread0/block arrives+spins (s_sleep backoff), others wait at
// __syncthreads. Slots memset-initialized host-side (1 tiny node). agg is its
// own phase again (R5: fusion kills gather latency hiding); fp32 hbuf dropped
// (self-term from bf16 h16; x fp32 for layer 0). Fallback = R7 path.

#define BN_EPS 1e-5f
#define NBKT 256     // dst buckets (dst>>9)
#define PCHUNK 3200  // edges per partition block
#define HBLK 128     // buckethist blocks
#define GRID 1024

__device__ __forceinline__ float bf2f(unsigned short u) {
  return __uint_as_float(((unsigned int)u) << 16);
}
__device__ __forceinline__ unsigned short f2bf(float x) {  // RNE
  unsigned int b = __float_as_uint(x);
  return (unsigned short)((b + 0x7FFFu + ((b >> 16) & 1u)) >> 16);
}

// single-use grid barrier, slot stride 16 ints (64B) to isolate cache lines
__device__ __forceinline__ void gbar(int* bar, int slot) {
  __syncthreads();
  if (threadIdx.x == 0) {
    int* p = &bar[slot * 16];
    __hip_atomic_fetch_add(p, 1, __ATOMIC_ACQ_REL, __HIP_MEMORY_SCOPE_AGENT);
    while (__hip_atomic_load(p, __ATOMIC_ACQUIRE, __HIP_MEMORY_SCOPE_AGENT) < GRID)
      __builtin_amdgcn_s_sleep(4);
  }
  __syncthreads();
}

// gather one row: self (fp32 if hf else bf16 h16) + sum of bf16 neighbors
__device__ __forceinline__ float gather_row(
    const float* __restrict__ hf, const unsigned short* __restrict__ h16,
    const int* __restrict__ offs, const int* __restrict__ csr, int rn, int lane) {
  float acc = hf ? hf[(size_t)rn * 64 + lane] : bf2f(h16[(size_t)rn * 64 + lane]);
  int e0 = offs[rn], e1 = offs[rn + 1];
  int e = e0;
  for (; e + 16 <= e1; e += 16) {
    int s0 = csr[e], s1 = csr[e + 1], s2 = csr[e + 2], s3 = csr[e + 3];
    int s4 = csr[e + 4], s5 = csr[e + 5], s6 = csr[e + 6], s7 = csr[e + 7];
    int s8 = csr[e + 8], s9 = csr[e + 9], sa = csr[e + 10], sb = csr[e + 11];
    int sc = csr[e + 12], sd = csr[e + 13], se = csr[e + 14], sf = csr[e + 15];
    float a0 = bf2f(h16[(size_t)s0 * 64 + lane]);
    float a1 = bf2f(h16[(size_t)s1 * 64 + lane]);
    float a2 = bf2f(h16[(size_t)s2 * 64 + lane]);
    float a3 = bf2f(h16[(size_t)s3 * 64 + lane]);
    float a4 = bf2f(h16[(size_t)s4 * 64 + lane]);
    float a5 = bf2f(h16[(size_t)s5 * 64 + lane]);
    float a6 = bf2f(h16[(size_t)s6 * 64 + lane]);
    float a7 = bf2f(h16[(size_t)s7 * 64 + lane]);
    float a8 = bf2f(h16[(size_t)s8 * 64 + lane]);
    float a9 = bf2f(h16[(size_t)s9 * 64 + lane]);
    float aa = bf2f(h16[(size_t)sa * 64 + lane]);
    float ab = bf2f(h16[(size_t)sb * 64 + lane]);
    float ac = bf2f(h16[(size_t)sc * 64 + lane]);
    float ad = bf2f(h16[(size_t)sd * 64 + lane]);
    float ae = bf2f(h16[(size_t)se * 64 + lane]);
    float af = bf2f(h16[(size_t)sf * 64 + lane]);
    acc += (((a0 + a1) + (a2 + a3)) + ((a4 + a5) + (a6 + a7))) +
           (((a8 + a9) + (aa + ab)) + ((ac + ad) + (ae + af)));
  }
  for (; e + 4 <= e1; e += 4) {
    int s0 = csr[e], s1 = csr[e + 1], s2 = csr[e + 2], s3 = csr[e + 3];
    float a0 = bf2f(h16[(size_t)s0 * 64 + lane]);
    float a1 = bf2f(h16[(size_t)s1 * 64 + lane]);
    float a2 = bf2f(h16[(size_t)s2 * 64 + lane]);
    float a3 = bf2f(h16[(size_t)s3 * 64 + lane]);
    acc += (a0 + a1) + (a2 + a3);
  }
  for (; e < e1; e++) acc += bf2f(h16[(size_t)csr[e] * 64 + lane]);
  return acc;
}

struct MegaP {
  const int* src;
  const int* dst;
  int E;
  int nparts;
  const float* x;
  const float* W1;
  const float* g1;
  const float* be1;
  const float* W2;
  const float* gbn;
  const float* bbn;
  const float* fcW;
  const float* fcb;
  float* out;
  int N;
  int* bar;
  int* bpart;
  int* bbase;
  int* bcur;
  int2* ep;
  int* offs;
  int* csr;
  float* vbuf;
  float* zbuf;
  float* logits;
  unsigned short* x16;
  unsigned short* h16;
  float* stats;
};

// 64-row tile GEMM body: As[64x68], Ws[64x68] in LDS; 2x8 acc per thread.
__device__ __forceinline__ void tile_gemm_stats(
    const float* __restrict__ As, const float* __restrict__ Ws,
    float* __restrict__ XT, float* __restrict__ zout,
    float* __restrict__ statsd, int n0, int N, int tid) {
  int tr = tid >> 3, tc = tid & 7;
  int ra = tr * 2;
  float acc[2][8];
#pragma unroll
  for (int i = 0; i < 2; i++)
#pragma unroll
    for (int j = 0; j < 8; j++) acc[i][j] = 0.f;
#pragma unroll 4
  for (int k = 0; k < 64; k++) {
    float a0 = As[ra * 68 + k];
    float a1 = As[(ra + 1) * 68 + k];
    const float* wk = &Ws[k * 68 + tc * 8];
    float4 w0 = *(const float4*)wk;
    float4 w1 = *(const float4*)(wk + 4);
    float wv[8] = {w0.x, w0.y, w0.z, w0.w, w1.x, w1.y, w1.z, w1.w};
#pragma unroll
    for (int j = 0; j < 8; j++) {
      acc[0][j] += a0 * wv[j];
      acc[1][j] += a1 * wv[j];
    }
  }
#pragma unroll
  for (int i = 0; i < 2; i++) {
    int rn = n0 + ra + i;
    if (rn < N) {
      float* zr = zout + (size_t)rn * 64 + tc * 8;
      *(float4*)zr = make_float4(acc[i][0], acc[i][1], acc[i][2], acc[i][3]);
      *(float4*)(zr + 4) = make_float4(acc[i][4], acc[i][5], acc[i][6], acc[i][7]);
    }
  }
  float cs[8], cq[8];
#pragma unroll
  for (int j = 0; j < 8; j++) {
    cs[j] = acc[0][j] + acc[1][j];
    cq[j] = acc[0][j] * acc[0][j] + acc[1][j] * acc[1][j];
  }
#pragma unroll
  for (int m = 8; m <= 32; m <<= 1) {
#pragma unroll
    for (int j = 0; j < 8; j++) {
      cs[j] += __shfl_xor(cs[j], m);
      cq[j] += __shfl_xor(cq[j], m);
    }
  }
  __syncthreads();
  int w = tid >> 6;
  if ((tid & 63) < 8) {
    int c = tc * 8;
#pragma unroll
    for (int j = 0; j < 8; j++) {
      XT[128 + w * 128 + c + j] = cs[j];
      XT[128 + w * 128 + 64 + c + j] = cq[j];
    }
  }
  __syncthreads();
  if (tid < 64) {
    float a = XT[128 + tid] + XT[256 + tid] + XT[384 + tid] + XT[512 + tid];
    float b = XT[192 + tid] + XT[320 + tid] + XT[448 + tid] + XT[576 + tid];
    atomicAdd(&statsd[tid], a);
    atomicAdd(&statsd[64 + tid], b);
  }
}

__global__ __launch_bounds__(256, 4) void k_mega(MegaP p) {
  __shared__ float smem[9344];  // As[4352] | Ws[4352] | XT[640] = 37376B
  int* ismem = (int*)smem;
  const int tid = threadIdx.x;
  const int bid = blockIdx.x;
  const int N = p.N;
  int bs = 0;  // barrier slot counter (uniform across blocks)

  // ---- P0: bucket histogram partials ----
  if (bid < HBLK) {
    ismem[tid] = 0;
    __syncthreads();
    for (int e = bid * 256 + tid; e < p.E; e += HBLK * 256)
      atomicAdd(&ismem[p.dst[e] >> 9], 1);
    __syncthreads();
    p.bpart[bid * NBKT + tid] = ismem[tid];
  }
  gbar(p.bar, bs++);

  // ---- P1: bucket scan -> bbase/bcur; zero stats ----
  if (bid == 0) {
    int s = 0;
    for (int i = 0; i < HBLK; i++) s += p.bpart[i * NBKT + tid];
    ismem[tid] = s;
    __syncthreads();
    for (int o = 1; o < 256; o <<= 1) {
      int add = (tid >= o) ? ismem[tid - o] : 0;
      __syncthreads();
      ismem[tid] += add;
      __syncthreads();
    }
    int excl = ismem[tid] - s;
    p.bbase[tid] = excl;
    p.bcur[tid] = excl;
    if (tid == 255) p.bbase[256] = ismem[255];
    p.stats[tid] = 0.f;
    p.stats[256 + tid] = 0.f;
    p.stats[512 + tid] = 0.f;
  }
  gbar(p.bar, bs++);

  // ---- P2: partition edges into buckets + head_init ----
  int nhead = (N + 255) >> 8;
  if (bid < p.nparts) {
    int* lh = ismem;
    int* lbase = ismem + 256;
    int* lcur = ismem + 512;
    int base = bid * PCHUNK;
    int end = min(base + PCHUNK, p.E);
    lh[tid] = 0;
    lcur[tid] = 0;
    __syncthreads();
    for (int e = base + tid; e < end; e += 256) atomicAdd(&lh[p.dst[e] >> 9], 1);
    __syncthreads();
    int c = lh[tid];
    lbase[tid] = c ? atomicAdd(&p.bcur[tid], c) : 0;
    __syncthreads();
    for (int e = base + tid; e < end; e += 256) {
      int d = p.dst[e];
      int b = d >> 9;
      int r = atomicAdd(&lcur[b], 1);
      p.ep[lbase[b] + r] = make_int2(p.src[e], d);
    }
  } else if (bid < p.nparts + nhead) {
    float* vs = smem;
    int n0 = (bid - p.nparts) << 8;
    int n = n0 + tid;
    float acc[10];
#pragma unroll
    for (int c = 0; c < 10; c++) acc[c] = 0.f;
#pragma unroll 1
    for (int fb = 0; fb < 64; fb += 16) {
      __syncthreads();
#pragma unroll
      for (int g = 0; g < 4; g++) {
        int r = g * 64 + (tid >> 2);
        int q = tid & 3;
        int rn = n0 + r;
        float4 t = make_float4(0.f, 0.f, 0.f, 0.f);
        if (rn < N) {
          t = *(const float4*)(p.x + (size_t)rn * 64 + fb + 4 * q);
          *(ushort4*)(p.x16 + (size_t)rn * 64 + fb + 4 * q) =
              make_ushort4(f2bf(t.x), f2bf(t.y), f2bf(t.z), f2bf(t.w));
        }
        int base = r * 17 + 4 * q;
        vs[base] = t.x;
        vs[base + 1] = t.y;
        vs[base + 2] = t.z;
        vs[base + 3] = t.w;
      }
      __syncthreads();
      for (int fc = 0; fc < 16; fc++) {
        int f = fb + fc;
        float vf = vs[tid * 17 + fc];
        const float* wr = p.fcW + f * 10;
#pragma unroll
        for (int c = 0; c < 10; c++) acc[c] += vf * wr[c];
      }
    }
    if (n < N) {
      float* lr = p.logits + (size_t)n * 10;
#pragma unroll
      for (int c = 0; c < 10; c++)
        lr[c] = acc[c] + (p.fcb[c] + p.fcb[10 + c] + p.fcb[20 + c] + p.fcb[30 + c]);
    }
  }
  gbar(p.bar, bs++);

  // ---- P3: per-bucket LDS counting sort -> offs, csr ----
  if (bid < NBKT) {
    int* cnt = ismem;
    int* ts = ismem + 512;
    int* cur = ismem + 768;
    int lo = p.bbase[bid], hi = p.bbase[bid + 1];
    cnt[tid] = 0;
    cnt[tid + 256] = 0;
    __syncthreads();
    for (int e = lo + tid; e < hi; e += 256) atomicAdd(&cnt[p.ep[e].y & 511], 1);
    __syncthreads();
    int c0 = cnt[2 * tid], c1 = cnt[2 * tid + 1];
    int s = c0 + c1;
    ts[tid] = s;
    __syncthreads();
    for (int o = 1; o < 256; o <<= 1) {
      int add = (tid >= o) ? ts[tid - o] : 0;
      __syncthreads();
      ts[tid] += add;
      __syncthreads();
    }
    int excl = ts[tid] - s;
    cur[2 * tid] = excl;
    cur[2 * tid + 1] = excl + c0;
    int n0 = bid << 9;
    p.offs[n0 + 2 * tid] = lo + excl;
    p.offs[n0 + 2 * tid + 1] = lo + excl + c0;
    __syncthreads();
    for (int e = lo + tid; e < hi; e += 256) {
      int2 q = p.ep[e];
      int pos = atomicAdd(&cur[q.y & 511], 1);
      p.csr[lo + pos] = q.x;
    }
  }
  gbar(p.bar, bs++);

  // ---- layers ----
  float* As = smem;
  float* Ws = smem + 4352;
  float* XT = smem + 8704;  // [0,128)=AB, [128,640)=fold scratch
  int ntile = (N + 63) >> 6;
  int lane = tid & 63;
  int wv = tid >> 6;
  for (int l = 0; l < 3; l++) {
    float* st1 = p.stats + (2 * l) * 128;
    float* st2 = p.stats + (2 * l + 1) * 128;
    const float* hf = (l == 0) ? p.x : nullptr;
    const unsigned short* h16 = (l == 0) ? p.x16 : p.h16;
    // ---- P4: aggregation, wave-per-node grid-stride -> vbuf ----
    {
      int gw = bid * 4 + wv;
      for (int n = gw; n < N; n += GRID * 4)
        p.vbuf[(size_t)n * 64 + lane] = gather_row(hf, h16, p.offs, p.csr, n, lane);
    }
    gbar(p.bar, bs++);
    // ---- P5: GEMM1 (no BN), vbuf -> zbuf, stats -> st1 ----
    {
      const float* W = p.W1 + l * 4096;
#pragma unroll
      for (int i = 0; i < 4; i++) {
        int g = tid + i * 256;
        int r = g >> 4, q = g & 15;
        float4 t = *(const float4*)(W + r * 64 + 4 * q);
        int b = r * 68 + 4 * q;
        Ws[b] = t.x; Ws[b + 1] = t.y; Ws[b + 2] = t.z; Ws[b + 3] = t.w;
      }
      for (int t = bid; t < ntile; t += GRID) {
        int n0 = t << 6;
        __syncthreads();
#pragma unroll
        for (int i = 0; i < 4; i++) {
          int g = tid + i * 256;
          int r = g >> 4, q = g & 15;
          int rn = n0 + r;
          float4 v = make_float4(0.f, 0.f, 0.f, 0.f);
          if (rn < N) v = *(const float4*)(p.vbuf + (size_t)rn * 64 + 4 * q);
          int bb = r * 68 + 4 * q;
          As[bb] = v.x; As[bb + 1] = v.y; As[bb + 2] = v.z; As[bb + 3] = v.w;
        }
        __syncthreads();
        tile_gemm_stats(As, Ws, XT, p.zbuf, st1, n0, N, tid);
      }
    }
    gbar(p.bar, bs++);
    // ---- P6: GEMM2 with BN(st1)+ReLU on input; in-place zbuf; stats->st2 ----
    {
      const float* W = p.W2 + l * 4096;
      if (tid < 64) {
        float inv_n = 1.f / (float)N;
        float mu = st1[tid] * inv_n;
        float var = st1[64 + tid] * inv_n - mu * mu;
        float A = rsqrtf(var + BN_EPS) * p.g1[l * 64 + tid];
        XT[tid] = A;
        XT[64 + tid] = p.be1[l * 64 + tid] - mu * A;
      }
#pragma unroll
      for (int i = 0; i < 4; i++) {
        int g = tid + i * 256;
        int r = g >> 4, q = g & 15;
        float4 t = *(const float4*)(W + r * 64 + 4 * q);
        int b = r * 68 + 4 * q;
        Ws[b] = t.x; Ws[b + 1] = t.y; Ws[b + 2] = t.z; Ws[b + 3] = t.w;
      }
      __syncthreads();
      for (int t = bid; t < ntile; t += GRID) {
        int n0 = t << 6;
#pragma unroll
        for (int i = 0; i < 4; i++) {
          int g = tid + i * 256;
          int r = g >> 4, q = g & 15;
          int rn = n0 + r;
          float4 v = make_float4(0.f, 0.f, 0.f, 0.f);
          if (rn < N) v = *(const float4*)(p.zbuf + (size_t)rn * 64 + 4 * q);
          float4 a = *(const float4*)(XT + 4 * q);
          float4 b = *(const float4*)(XT + 64 + 4 * q);
          v.x = fmaxf(v.x * a.x + b.x, 0.f);
          v.y = fmaxf(v.y * a.y + b.y, 0.f);
          v.z = fmaxf(v.z * a.z + b.z, 0.f);
          v.w = fmaxf(v.w * a.w + b.w, 0.f);
          int bb = r * 68 + 4 * q;
          As[bb] = v.x; As[bb + 1] = v.y; As[bb + 2] = v.z; As[bb + 3] = v.w;
        }
        __syncthreads();
        tile_gemm_stats(As, Ws, XT, p.zbuf, st2, n0, N, tid);
        __syncthreads();
      }
    }
    gbar(p.bar, bs++);
    // ---- P7: BN(st2)+ReLU -> h16; logits += h@fcWl; final: log-softmax ----
    {
      if (tid < 64) {
        float inv_n = 1.f / (float)N;
        float mu = st2[tid] * inv_n;
        float var = st2[64 + tid] * inv_n - mu * mu;
        float A = rsqrtf(var + BN_EPS) * p.gbn[l * 64 + tid];
        XT[tid] = A;
        XT[64 + tid] = p.bbn[l * 64 + tid] - mu * A;
      }
      __syncthreads();
      if (bid < nhead) {
        const float* fcWl = p.fcW + (l + 1) * 640;
        int dofinal = (l == 2) ? 1 : 0;
        float* vs = As;
        int n0 = bid << 8;
        int n = n0 + tid;
        float acc[10];
#pragma unroll
        for (int c = 0; c < 10; c++) acc[c] = 0.f;
#pragma unroll 1
        for (int fb = 0; fb < 64; fb += 16) {
          __syncthreads();
#pragma unroll
          for (int g = 0; g < 4; g++) {
            int r = g * 64 + (tid >> 2);
            int q = tid & 3;
            int rn = n0 + r;
            float4 t = (rn < N) ? *(const float4*)(p.zbuf + (size_t)rn * 64 + fb + 4 * q)
                                : make_float4(0.f, 0.f, 0.f, 0.f);
            int base = r * 17 + 4 * q;
            vs[base] = t.x;
            vs[base + 1] = t.y;
            vs[base + 2] = t.z;
            vs[base + 3] = t.w;
          }
          __syncthreads();
          float tl[16];
#pragma unroll
          for (int fc = 0; fc < 16; fc++) {
            int f = fb + fc;
            float val = vs[tid * 17 + fc] * XT[f] + XT[64 + f];
            tl[fc] = fmaxf(val, 0.f);
            const float* wr = fcWl + f * 10;
#pragma unroll
            for (int c = 0; c < 10; c++) acc[c] += tl[fc] * wr[c];
          }
          if (!dofinal) {
            __syncthreads();
#pragma unroll
            for (int fc = 0; fc < 16; fc++) vs[tid * 17 + fc] = tl[fc];
            __syncthreads();
#pragma unroll
            for (int g = 0; g < 4; g++) {
              int r = g * 64 + (tid >> 2);
              int q = tid & 3;
              int rn = n0 + r;
              if (rn < N) {
                int base = r * 17 + 4 * q;
                *(ushort4*)(p.h16 + (size_t)rn * 64 + fb + 4 * q) =
                    make_ushort4(f2bf(vs[base]), f2bf(vs[base + 1]),
                                 f2bf(vs[base + 2]), f2bf(vs[base + 3]));
              }
            }
          }
        }
        if (n < N) {
          float* lr = p.logits + (size_t)n * 10;
          if (!dofinal) {
#pragma unroll
            for (int c = 0; c < 10; c++) lr[c] += acc[c];
          } else {
            float v[10];
            float m = -INFINITY;
#pragma unroll
            for (int c = 0; c < 10; c++) {
              v[c] = lr[c] + acc[c];
              m = fmaxf(m, v[c]);
            }
            float s = 0.f;
#pragma unroll
            for (int c = 0; c < 10; c++) s += expf(v[c] - m);
            float lg = logf(s) + m;
            float* orow = p.out + (size_t)n * 10;
#pragma unroll
            for (int c = 0; c < 10; c++) orow[c] = v[c] - lg;
          }
        }
      }
    }
    if (l < 2) gbar(p.bar, bs++);
  }
}

// ================= fallback (R7) kernels =================

__global__ __launch_bounds__(256) void k_buckethist(const int* __restrict__ dst,
                                                    int* __restrict__ bpart, int E) {
  __shared__ int lh[NBKT];
  lh[threadIdx.x] = 0;
  __syncthreads();
  for (int e = blockIdx.x * 256 + threadIdx.x; e < E; e += HBLK * 256)
    atomicAdd(&lh[dst[e] >> 9], 1);
  __syncthreads();
  bpart[blockIdx.x * NBKT + threadIdx.x] = lh[threadIdx.x];
}

__global__ __launch_bounds__(256) void k_scanblock2(const int* __restrict__ bpart,
                                                    int* __restrict__ bbase,
                                                    int* __restrict__ bcur,
                                                    float* __restrict__ stats, int E) {
  __shared__ int ts[256];
  int t = threadIdx.x;
  int s = 0;
  for (int i = 0; i < HBLK; i++) s += bpart[i * NBKT + t];
  ts[t] = s;
  __syncthreads();
  for (int o = 1; o < 256; o <<= 1) {
    int add = (t >= o) ? ts[t - o] : 0;
    __syncthreads();
    ts[t] += add;
    __syncthreads();
  }
  int excl = ts[t] - s;
  bbase[t] = excl;
  bcur[t] = excl;
  if (t == 255) bbase[256] = ts[255];
  stats[t] = 0.f;
  stats[256 + t] = 0.f;
  stats[512 + t] = 0.f;
}

__global__ __launch_bounds__(256) void k_part_head(
    const int* __restrict__ src, const int* __restrict__ dst,
    int* __restrict__ bcur, int2* __restrict__ ep, int E, int nparts,
    const float* __restrict__ x, const float* __restrict__ fcW0,
    const float* __restrict__ fcb, float* __restrict__ logits,
    unsigned short* __restrict__ x16, int N) {
  __shared__ char smem[256 * 17 * 4];
  int tid = threadIdx.x;
  if ((int)blockIdx.x < nparts) {
    int* lh = (int*)smem;
    int* lbase = lh + NBKT;
    int* lcur = lh + 2 * NBKT;
    int base = blockIdx.x * PCHUNK;
    int end = min(base + PCHUNK, E);
    lh[tid] = 0;
    lcur[tid] = 0;
    __syncthreads();
    for (int e = base + tid; e < end; e += 256) atomicAdd(&lh[dst[e] >> 9], 1);
    __syncthreads();
    int c = lh[tid];
    lbase[tid] = c ? atomicAdd(&bcur[tid], c) : 0;
    __syncthreads();
    for (int e = base + tid; e < end; e += 256) {
      int d = dst[e];
      int b = d >> 9;
      int r = atomicAdd(&lcur[b], 1);
      ep[lbase[b] + r] = make_int2(src[e], d);
    }
  } else {
    float* vs = (float*)smem;
    int n0 = (blockIdx.x - nparts) * 256;
    int n = n0 + tid;
    float acc[10];
#pragma unroll
    for (int c = 0; c < 10; c++) acc[c] = 0.f;
#pragma unroll 1
    for (int fb = 0; fb < 64; fb += 16) {
      __syncthreads();
#pragma unroll
      for (int g = 0; g < 4; g++) {
        int r = g * 64 + (tid >> 2);
        int q = tid & 3;
        int rn = n0 + r;
        float4 t = make_float4(0.f, 0.f, 0.f, 0.f);
        if (rn < N) {
          t = *(const float4*)(x + (size_t)rn * 64 + fb + 4 * q);
          *(ushort4*)(x16 + (size_t)rn * 64 + fb + 4 * q) =
              make_ushort4(f2bf(t.x), f2bf(t.y), f2bf(t.z), f2bf(t.w));
        }
        int base = r * 17 + 4 * q;
        vs[base] = t.x;
        vs[base + 1] = t.y;
        vs[base + 2] = t.z;
        vs[base + 3] = t.w;
      }
      __syncthreads();
      for (int fc = 0; fc < 16; fc++) {
        int f = fb + fc;
        float vf = vs[tid * 17 + fc];
        const float* wr = fcW0 + f * 10;
#pragma unroll
        for (int c = 0; c < 10; c++) acc[c] += vf * wr[c];
      }
    }
    if (n < N) {
      float* lr = logits + (size_t)n * 10;
#pragma unroll
      for (int c = 0; c < 10; c++)
        lr[c] = acc[c] + (fcb[c] + fcb[10 + c] + fcb[20 + c] + fcb[30 + c]);
    }
  }
}

__global__ __launch_bounds__(256) void k_bucketsort(
    const int2* __restrict__ ep, const int* __restrict__ bbase,
    int* __restrict__ offs, int* __restrict__ csr) {
  __shared__ int cnt[512];
  __shared__ int ts[256];
  __shared__ int cur[512];
  int t = threadIdx.x;
  int b = blockIdx.x;
  int lo = bbase[b], hi = bbase[b + 1];
  cnt[t] = 0;
  cnt[t + 256] = 0;
  __syncthreads();
  for (int e = lo + t; e < hi; e += 256) atomicAdd(&cnt[ep[e].y & 511], 1);
  __syncthreads();
  int c0 = cnt[2 * t], c1 = cnt[2 * t + 1];
  int s = c0 + c1;
  ts[t] = s;
  __syncthreads();
  for (int o = 1; o < 256; o <<= 1) {
    int add = (t >= o) ? ts[t - o] : 0;
    __syncthreads();
    ts[t] += add;
    __syncthreads();
  }
  int excl = ts[t] - s;
  cur[2 * t] = excl;
  cur[2 * t + 1] = excl + c0;
  int n0 = b * 512;
  offs[n0 + 2 * t] = lo + excl;
  offs[n0 + 2 * t + 1] = lo + excl + c0;
  __syncthreads();
  for (int e = lo + t; e < hi; e += 256) {
    int2 p = ep[e];
    int pos = atomicAdd(&cur[p.y & 511], 1);
    csr[lo + pos] = p.x;
  }
}

__global__ __launch_bounds__(256) void k_agg(
    const float* __restrict__ h, const unsigned short* __restrict__ h16,
    const int* __restrict__ offs, const int* __restrict__ csr,
    float* __restrict__ vout, int N) {
  int gid = blockIdx.x * blockDim.x + threadIdx.x;
  int wid = __builtin_amdgcn_readfirstlane(gid >> 6);
  int lane = threadIdx.x & 63;
  if (wid >= N) return;
  vout[(size_t)wid * 64 + lane] = gather_row(h, h16, offs, csr, wid, lane);
}

__global__ __launch_bounds__(256) void k_gemm2(
    const float* __restrict__ vin, float* __restrict__ zout,
    const float* __restrict__ W,
    const float* __restrict__ stats_in, const float* __restrict__ gv,
    const float* __restrict__ bev, int dobn,
    float* __restrict__ stats_out, int N) {
  __shared__ float As[128 * 68];
  __shared__ float Ws[64 * 68];
  __shared__ float ABs[128];
  int tid = threadIdx.x;
  int n0 = blockIdx.x * 128;
  if (dobn) {
    if (tid < 64) {
      float inv_n = 1.f / (float)N;
      float mu = stats_in[tid] * inv_n;
      float var = stats_in[64 + tid] * inv_n - mu * mu;
      float A = rsqrtf(var + BN_EPS) * gv[tid];
      ABs[tid] = A;
      ABs[64 + tid] = bev[tid] - mu * A;
    }
    __syncthreads();
  }
#pragma unroll
  for (int i = 0; i < 4; i++) {
    int g = tid + i * 256;
    int r = g >> 4, q = g & 15;
    float4 t = *(const float4*)(W + r * 64 + 4 * q);
    int base = r * 68 + 4 * q;
    Ws[base] = t.x; Ws[base + 1] = t.y; Ws[base + 2] = t.z; Ws[base + 3] = t.w;
  }
#pragma unroll
  for (int i = 0; i < 8; i++) {
    int g = tid + i * 256;
    int r = g >> 4, q = g & 15;
    int rn = n0 + r;
    float4 t = make_float4(0.f, 0.f, 0.f, 0.f);
    if (rn < N) t = *(const float4*)(vin + (size_t)rn * 64 + 4 * q);
    if (dobn) {
      float4 a = *(const float4*)(ABs + 4 * q);
      float4 b = *(const float4*)(ABs + 64 + 4 * q);
      t.x = fmaxf(t.x * a.x + b.x, 0.f);
      t.y = fmaxf(t.y * a.y + b.y, 0.f);
      t.z = fmaxf(t.z * a.z + b.z, 0.f);
      t.w = fmaxf(t.w * a.w + b.w, 0.f);
    }
    int base = r * 68 + 4 * q;
    As[base] = t.x; As[base + 1] = t.y; As[base + 2] = t.z; As[base + 3] = t.w;
  }
  __syncthreads();
  int tr = tid >> 3, tc = tid & 7;
  int ra = tr * 4;
  float acc[4][8];
#pragma unroll
  for (int i = 0; i < 4; i++)
#pragma unroll
    for (int j = 0; j < 8; j++) acc[i][j] = 0.f;
#pragma unroll 4
  for (int k = 0; k < 64; k++) {
    float av[4];
#pragma unroll
    for (int i = 0; i < 4; i++) av[i] = As[(ra + i) * 68 + k];
    const float* wk = &Ws[k * 68 + tc * 8];
    float4 w0 = *(const float4*)wk;
    float4 w1 = *(const float4*)(wk + 4);
    float wv[8] = {w0.x, w0.y, w0.z, w0.w, w1.x, w1.y, w1.z, w1.w};
#pragma unroll
    for (int i = 0; i < 4; i++)
#pragma unroll
      for (int j = 0; j < 8; j++) acc[i][j] += av[i] * wv[j];
  }
#pragma unroll
  for (int i = 0; i < 4; i++) {
    int rn = n0 + ra + i;
    if (rn < N) {
      float* zr = zout + (size_t)rn * 64 + tc * 8;
      *(float4*)zr = make_float4(acc[i][0], acc[i][1], acc[i][2], acc[i][3]);
      *(float4*)(zr + 4) = make_float4(acc[i][4], acc[i][5], acc[i][6], acc[i][7]);
    }
  }
  float cs[8], cq[8];
#pragma unroll
  for (int j = 0; j < 8; j++) {
    float s = 0.f, q = 0.f;
#pragma unroll
    for (int i = 0; i < 4; i++) {
      s += acc[i][j];
      q += acc[i][j] * acc[i][j];
    }
    cs[j] = s;
    cq[j] = q;
  }
#pragma unroll
  for (int m = 8; m <= 32; m <<= 1) {
#pragma unroll
    for (int j = 0; j < 8; j++) {
      cs[j] += __shfl_xor(cs[j], m);
      cq[j] += __shfl_xor(cq[j], m);
    }
  }
  __syncthreads();
  int w = tid >> 6;
  if ((tid & 63) < 8) {
    int c = tc * 8;
#pragma unroll
    for (int j = 0; j < 8; j++) {
      Ws[w * 128 + c + j] = cs[j];
      Ws[w * 128 + 64 + c + j] = cq[j];
    }
  }
  __syncthreads();
  if (tid < 64) {
    float a = Ws[tid] + Ws[128 + tid] + Ws[256 + tid] + Ws[384 + tid];
    float b = Ws[64 + tid] + Ws[192 + tid] + Ws[320 + tid] + Ws[448 + tid];
    atomicAdd(&stats_out[tid], a);
    atomicAdd(&stats_out[64 + tid], b);
  }
}

__global__ __launch_bounds__(256) void k_bn_head(
    const float* __restrict__ z,
    const float* __restrict__ stats_in, const float* __restrict__ gv,
    const float* __restrict__ bev,
    float* __restrict__ hout, unsigned short* __restrict__ h16out,
    const float* __restrict__ fcWl, float* __restrict__ logits,
    float* __restrict__ out, int dofinal, int N) {
  __shared__ float vs[256 * 17];
  __shared__ float ABs[128];
  int tid = threadIdx.x;
  if (tid < 64) {
    float inv_n = 1.f / (float)N;
    float mu = stats_in[tid] * inv_n;
    float var = stats_in[64 + tid] * inv_n - mu * mu;
    float A = rsqrtf(var + BN_EPS) * gv[tid];
    ABs[tid] = A;
    ABs[64 + tid] = bev[tid] - mu * A;
  }
  int n0 = blockIdx.x * 256;
  int n = n0 + tid;
  float acc[10];
#pragma unroll
  for (int c = 0; c < 10; c++) acc[c] = 0.f;
#pragma unroll 1
  for (int fb = 0; fb < 64; fb += 16) {
    __syncthreads();
#pragma unroll
    for (int g = 0; g < 4; g++) {
      int r = g * 64 + (tid >> 2);
      int q = tid & 3;
      int rn = n0 + r;
      float4 t = (rn < N) ? *(const float4*)(z + (size_t)rn * 64 + fb + 4 * q)
                          : make_float4(0.f, 0.f, 0.f, 0.f);
      int base = r * 17 + 4 * q;
      vs[base] = t.x;
      vs[base + 1] = t.y;
      vs[base + 2] = t.z;
      vs[base + 3] = t.w;
    }
    __syncthreads();
    float tl[16];
#pragma unroll
    for (int fc = 0; fc < 16; fc++) {
      int f = fb + fc;
      float val = vs[tid * 17 + fc] * ABs[f] + ABs[64 + f];
      tl[fc] = fmaxf(val, 0.f);
      const float* wr = fcWl + f * 10;
#pragma unroll
      for (int c = 0; c < 10; c++) acc[c] += tl[fc] * wr[c];
    }
    if (!dofinal) {
      __syncthreads();
#pragma unroll
      for (int fc = 0; fc < 16; fc++) vs[tid * 17 + fc] = tl[fc];
      __syncthreads();
#pragma unroll
      for (int g = 0; g < 4; g++) {
        int r = g * 64 + (tid >> 2);
        int q = tid & 3;
        int rn = n0 + r;
        if (rn < N) {
          int base = r * 17 + 4 * q;
          float4 t = make_float4(vs[base], vs[base + 1], vs[base + 2], vs[base + 3]);
          *(float4*)(hout + (size_t)rn * 64 + fb + 4 * q) = t;
          *(ushort4*)(h16out + (size_t)rn * 64 + fb + 4 * q) =
              make_ushort4(f2bf(t.x), f2bf(t.y), f2bf(t.z), f2bf(t.w));
        }
      }
    }
  }
  if (n < N) {
    float* lr = logits + (size_t)n * 10;
    if (!dofinal) {
#pragma unroll
      for (int c = 0; c < 10; c++) lr[c] += acc[c];
    } else {
      float v[10];
      float m = -INFINITY;
#pragma unroll
      for (int c = 0; c < 10; c++) {
        v[c] = lr[c] + acc[c];
        m = fmaxf(m, v[c]);
      }
      float s = 0.f;
#pragma unroll
      for (int c = 0; c < 10; c++) s += expf(v[c] - m);
      float l = logf(s) + m;
      float* orow = out + (size_t)n * 10;
#pragma unroll
      for (int c = 0; c < 10; c++) orow[c] = v[c] - l;
    }
  }
}

extern "C" void kernel_launch(void* const* d_in, const int* in_sizes, int n_in,
                              void* d_out, int out_size, void* d_ws, size_t ws_size,
                              hipStream_t stream) {
  const float* x = (const float*)d_in[0];
  const int* ei = (const int*)d_in[1];
  const float* W1 = (const float*)d_in[2];
  const float* g1 = (const float*)d_in[4];
  const float* be1 = (const float*)d_in[5];
  const float* W2 = (const float*)d_in[6];
  const float* gbn = (const float*)d_in[8];
  const float* bbn = (const float*)d_in[9];
  const float* fcW = (const float*)d_in[10];
  const float* fcb = (const float*)d_in[11];
  float* out = (float*)d_out;

  const int N = in_sizes[0] / 64;
  const int E = in_sizes[1] / 2;
  const int* src = ei;
  const int* dst = ei + E;

  char* ws = (char*)d_ws;
  size_t off = 0;
  auto alloc = [&](size_t bytes) -> void* {
    void* p = ws + off;
    off = (off + bytes + 255) & ~(size_t)255;
    return p;
  };
  int* bar = (int*)alloc(64 * 16 * 4);  // barrier slots (memset below)
  float* stats = (float*)alloc(6 * 128 * 4);
  int* bpart = (int*)alloc((size_t)HBLK * NBKT * 4);
  int* bbase = (int*)alloc((NBKT + 1) * 4);
  int* bcur = (int*)alloc(NBKT * 4);
  int* offs = (int*)alloc(((size_t)NBKT * 512 + 1) * 4);
  int* csr = (int*)alloc((size_t)E * 4);
  float* hbuf = (float*)alloc((size_t)N * 64 * 4);  // fallback only
  float* zbuf = (float*)alloc((size_t)N * 64 * 4);
  float* logits = (float*)alloc((size_t)N * 10 * 4);
  unsigned short* x16 = (unsigned short*)alloc((size_t)N * 64 * 2);
  unsigned short* h16 = (unsigned short*)alloc((size_t)N * 64 * 2);
  float* vbuf = (float*)alloc((size_t)N * 64 * 4);
  int2* ep = (int2*)vbuf;  // alias: ep dead before vbuf first written
  (void)ws_size;
  (void)n_in;
  (void)out_size;

  int nparts = (E + PCHUNK - 1) / PCHUNK;
  hipMemsetAsync(bar, 0, 64 * 16 * 4, stream);

  MegaP p;
  p.src = src; p.dst = dst; p.E = E; p.nparts = nparts;
  p.x = x; p.W1 = W1; p.g1 = g1; p.be1 = be1; p.W2 = W2;
  p.gbn = gbn; p.bbn = bbn; p.fcW = fcW; p.fcb = fcb; p.out = out; p.N = N;
  p.bar = bar; p.bpart = bpart; p.bbase = bbase; p.bcur = bcur; p.ep = ep;
  p.offs = offs; p.csr = csr; p.vbuf = vbuf; p.zbuf = zbuf;
  p.logits = logits; p.x16 = x16; p.h16 = h16; p.stats = stats;

  void* args[] = {(void*)&p};
  hipError_t err = hipLaunchCooperativeKernel((const void*)k_mega, dim3(GRID),
                                              dim3(256), args, 0, stream);
  if (err != hipSuccess) {
    (void)hipGetLastError();  // clear sticky error, use fallback path
    int nb = (N + 255) / 256;
    int gb = (N + 127) / 128;
    k_buckethist<<<HBLK, 256, 0, stream>>>(dst, bpart, E);
    k_scanblock2<<<1, 256, 0, stream>>>(bpart, bbase, bcur, stats, E);
    k_part_head<<<nparts + nb, 256, 0, stream>>>(src, dst, bcur, ep, E, nparts, x,
                                                 fcW, fcb, logits, x16, N);
    k_bucketsort<<<NBKT, 256, 0, stream>>>(ep, bbase, offs, csr);
    const float* hin = x;
    const unsigned short* hin16 = x16;
    for (int l = 0; l < 3; l++) {
      float* st1 = stats + (2 * l) * 128;
      float* st2 = stats + (2 * l + 1) * 128;
      k_agg<<<(N * 64 + 255) / 256, 256, 0, stream>>>(hin, hin16, offs, csr, vbuf, N);
      k_gemm2<<<gb, 256, 0, stream>>>(vbuf, zbuf, W1 + l * 4096, nullptr, nullptr,
                                      nullptr, 0, st1, N);
      k_gemm2<<<gb, 256, 0, stream>>>(zbuf, zbuf, W2 + l * 4096, st1, g1 + l * 64,
                                      be1 + l * 64, 1, st2, N);
      int dofinal = (l == 2) ? 1 : 0;
      k_bn_head<<<nb, 256, 0, stream>>>(zbuf, st2, gbn + l * 64, bbn + l * 64, hbuf,
                                        h16, fcW + (l + 1) * 640, logits, out,
                                        dofinal, N);
      hin = hbuf;
      hin16 = h16;
    }
  }
}

// Round 10
// 621.208 us; speedup vs baseline: 9.1961x; 9.1961x over previous
//
#include <hip/hip_runtime.h>
#include <math.h>

// GIN: N=100000 nodes, E=1600000 edges, F=D=64, L=3 layers, C=10 classes.
// R10: persistent-kernel abandoned (R8/R9: grid-barrier acquire-polls thrash
// L1 device-wide -> 1.75GB traffic, 4-10x slowdown; structural). Back to the
// proven R7 multi-launch skeleton, minus two kernels:
//   - GEMM2 writes a bf16 z16 shadow (pre-BN z2) in its epilogue.
//   - bn_head for layers 0/1 is folded into the NEXT layer's aggregation
//     (k_aggbn): AB from st2 in prologue, BN+ReLU applied inline during the
//     gather (self from fp32 zbuf, neighbors from bf16 z16), JK-head logits
//     via 10 wave-butterflies (lane = h column), v written for GEMM1.
//   - fp32 hbuf eliminated. Final layer keeps bn_head (dofinal: softmax).
// 14 launches.

#define BN_EPS 1e-5f
#define NBKT 256     // dst buckets (dst>>9)
#define PCHUNK 8192  // edges per partition block
#define HBLK 128     // buckethist blocks

__device__ __forceinline__ float bf2f(unsigned short u) {
  return __uint_as_float(((unsigned int)u) << 16);
}
__device__ __forceinline__ unsigned short f2bf(float x) {  // RNE
  unsigned int b = __float_as_uint(x);
  return (unsigned short)((b + 0x7FFFu + ((b >> 16) & 1u)) >> 16);
}

// ---------- CSR build ----------

__global__ __launch_bounds__(256) void k_buckethist(const int* __restrict__ dst,
                                                    int* __restrict__ bpart, int E) {
  __shared__ int lh[NBKT];
  lh[threadIdx.x] = 0;
  __syncthreads();
  for (int e = blockIdx.x * 256 + threadIdx.x; e < E; e += HBLK * 256)
    atomicAdd(&lh[dst[e] >> 9], 1);
  __syncthreads();
  bpart[blockIdx.x * NBKT + threadIdx.x] = lh[threadIdx.x];
}

__global__ __launch_bounds__(256) void k_scanblock2(const int* __restrict__ bpart,
                                                    int* __restrict__ bbase,
                                                    int* __restrict__ bcur,
                                                    float* __restrict__ stats, int E) {
  __shared__ int ts[256];
  int t = threadIdx.x;
  int s = 0;
  for (int i = 0; i < HBLK; i++) s += bpart[i * NBKT + t];
  ts[t] = s;
  __syncthreads();
  for (int o = 1; o < 256; o <<= 1) {
    int add = (t >= o) ? ts[t - o] : 0;
    __syncthreads();
    ts[t] += add;
    __syncthreads();
  }
  int excl = ts[t] - s;
  bbase[t] = excl;
  bcur[t] = excl;
  if (t == 255) bbase[256] = ts[255];
  stats[t] = 0.f;
  stats[256 + t] = 0.f;
  stats[512 + t] = 0.f;
}

// combined dispatch: blocks [0,nparts) partition edges; rest do head_init.
__global__ __launch_bounds__(256) void k_part_head(
    const int* __restrict__ src, const int* __restrict__ dst,
    int* __restrict__ bcur, int2* __restrict__ ep, int E, int nparts,
    const float* __restrict__ x, const float* __restrict__ fcW0,
    const float* __restrict__ fcb, float* __restrict__ logits,
    unsigned short* __restrict__ x16, int N) {
  __shared__ char smem[256 * 17 * 4];
  int tid = threadIdx.x;
  if ((int)blockIdx.x < nparts) {
    int* lh = (int*)smem;
    int* lbase = lh + NBKT;
    int* lcur = lh + 2 * NBKT;
    int base = blockIdx.x * PCHUNK;
    int end = min(base + PCHUNK, E);
    lh[tid] = 0;
    lcur[tid] = 0;
    __syncthreads();
    for (int e = base + tid; e < end; e += 256) atomicAdd(&lh[dst[e] >> 9], 1);
    __syncthreads();
    int c = lh[tid];
    lbase[tid] = c ? atomicAdd(&bcur[tid], c) : 0;
    __syncthreads();
    for (int e = base + tid; e < end; e += 256) {
      int d = dst[e];
      int b = d >> 9;
      int r = atomicAdd(&lcur[b], 1);
      ep[lbase[b] + r] = make_int2(src[e], d);
    }
  } else {
    float* vs = (float*)smem;
    int n0 = (blockIdx.x - nparts) * 256;
    int n = n0 + tid;
    float acc[10];
#pragma unroll
    for (int c = 0; c < 10; c++) acc[c] = 0.f;
#pragma unroll 1
    for (int fb = 0; fb < 64; fb += 16) {
      __syncthreads();
#pragma unroll
      for (int g = 0; g < 4; g++) {
        int r = g * 64 + (tid >> 2);
        int q = tid & 3;
        int rn = n0 + r;
        float4 t = make_float4(0.f, 0.f, 0.f, 0.f);
        if (rn < N) {
          t = *(const float4*)(x + (size_t)rn * 64 + fb + 4 * q);
          *(ushort4*)(x16 + (size_t)rn * 64 + fb + 4 * q) =
              make_ushort4(f2bf(t.x), f2bf(t.y), f2bf(t.z), f2bf(t.w));
        }
        int base = r * 17 + 4 * q;
        vs[base] = t.x;
        vs[base + 1] = t.y;
        vs[base + 2] = t.z;
        vs[base + 3] = t.w;
      }
      __syncthreads();
      for (int fc = 0; fc < 16; fc++) {
        int f = fb + fc;
        float vf = vs[tid * 17 + fc];
        const float* wr = fcW0 + f * 10;
#pragma unroll
        for (int c = 0; c < 10; c++) acc[c] += vf * wr[c];
      }
    }
    if (n < N) {
      float* lr = logits + (size_t)n * 10;
#pragma unroll
      for (int c = 0; c < 10; c++)
        lr[c] = acc[c] + (fcb[c] + fcb[10 + c] + fcb[20 + c] + fcb[30 + c]);
    }
  }
}

__global__ __launch_bounds__(256) void k_bucketsort(
    const int2* __restrict__ ep, const int* __restrict__ bbase,
    int* __restrict__ offs, int* __restrict__ csr) {
  __shared__ int cnt[512];
  __shared__ int ts[256];
  __shared__ int cur[512];
  int t = threadIdx.x;
  int b = blockIdx.x;
  int lo = bbase[b], hi = bbase[b + 1];
  cnt[t] = 0;
  cnt[t + 256] = 0;
  __syncthreads();
  for (int e = lo + t; e < hi; e += 256) atomicAdd(&cnt[ep[e].y & 511], 1);
  __syncthreads();
  int c0 = cnt[2 * t], c1 = cnt[2 * t + 1];
  int s = c0 + c1;
  ts[t] = s;
  __syncthreads();
  for (int o = 1; o < 256; o <<= 1) {
    int add = (t >= o) ? ts[t - o] : 0;
    __syncthreads();
    ts[t] += add;
    __syncthreads();
  }
  int excl = ts[t] - s;
  cur[2 * t] = excl;
  cur[2 * t + 1] = excl + c0;
  int n0 = b * 512;
  offs[n0 + 2 * t] = lo + excl;
  offs[n0 + 2 * t + 1] = lo + excl + c0;
  __syncthreads();
  for (int e = lo + t; e < hi; e += 256) {
    int2 p = ep[e];
    int pos = atomicAdd(&cur[p.y & 511], 1);
    csr[lo + pos] = p.x;
  }
}

// ---------- compute ----------

// 16-deep bf16 neighbor gather (no BN), returns sum of neighbors
__device__ __forceinline__ float gather_plain(
    const unsigned short* __restrict__ h16, const int* __restrict__ csr,
    int e0, int e1, int lane) {
  float acc = 0.f;
  int e = e0;
  for (; e + 16 <= e1; e += 16) {
    int s0 = csr[e], s1 = csr[e + 1], s2 = csr[e + 2], s3 = csr[e + 3];
    int s4 = csr[e + 4], s5 = csr[e + 5], s6 = csr[e + 6], s7 = csr[e + 7];
    int s8 = csr[e + 8], s9 = csr[e + 9], sa = csr[e + 10], sb = csr[e + 11];
    int sc = csr[e + 12], sd = csr[e + 13], se = csr[e + 14], sf = csr[e + 15];
    float a0 = bf2f(h16[(size_t)s0 * 64 + lane]);
    float a1 = bf2f(h16[(size_t)s1 * 64 + lane]);
    float a2 = bf2f(h16[(size_t)s2 * 64 + lane]);
    float a3 = bf2f(h16[(size_t)s3 * 64 + lane]);
    float a4 = bf2f(h16[(size_t)s4 * 64 + lane]);
    float a5 = bf2f(h16[(size_t)s5 * 64 + lane]);
    float a6 = bf2f(h16[(size_t)s6 * 64 + lane]);
    float a7 = bf2f(h16[(size_t)s7 * 64 + lane]);
    float a8 = bf2f(h16[(size_t)s8 * 64 + lane]);
    float a9 = bf2f(h16[(size_t)s9 * 64 + lane]);
    float aa = bf2f(h16[(size_t)sa * 64 + lane]);
    float ab = bf2f(h16[(size_t)sb * 64 + lane]);
    float ac = bf2f(h16[(size_t)sc * 64 + lane]);
    float ad = bf2f(h16[(size_t)sd * 64 + lane]);
    float ae = bf2f(h16[(size_t)se * 64 + lane]);
    float af = bf2f(h16[(size_t)sf * 64 + lane]);
    acc += (((a0 + a1) + (a2 + a3)) + ((a4 + a5) + (a6 + a7))) +
           (((a8 + a9) + (aa + ab)) + ((ac + ad) + (ae + af)));
  }
  for (; e + 4 <= e1; e += 4) {
    int s0 = csr[e], s1 = csr[e + 1], s2 = csr[e + 2], s3 = csr[e + 3];
    float a0 = bf2f(h16[(size_t)s0 * 64 + lane]);
    float a1 = bf2f(h16[(size_t)s1 * 64 + lane]);
    float a2 = bf2f(h16[(size_t)s2 * 64 + lane]);
    float a3 = bf2f(h16[(size_t)s3 * 64 + lane]);
    acc += (a0 + a1) + (a2 + a3);
  }
  for (; e < e1; e++) acc += bf2f(h16[(size_t)csr[e] * 64 + lane]);
  return acc;
}

// layer-0 aggregation: v[n] = x[n] (fp32) + sum bf16 x16[src]
__global__ __launch_bounds__(256) void k_agg(
    const float* __restrict__ h, const unsigned short* __restrict__ h16,
    const int* __restrict__ offs, const int* __restrict__ csr,
    float* __restrict__ vout, int N) {
  int gid = blockIdx.x * blockDim.x + threadIdx.x;
  int wid = __builtin_amdgcn_readfirstlane(gid >> 6);
  int lane = threadIdx.x & 63;
  if (wid >= N) return;
  float acc = h[(size_t)wid * 64 + lane] +
              gather_plain(h16, csr, offs[wid], offs[wid + 1], lane);
  vout[(size_t)wid * 64 + lane] = acc;
}

// fused BN+ReLU aggregation + JK head for layers 1..L-1:
//  h[n][lane] = relu(z[n][lane]*A+B); v[n] = h[n] + sum relu(bf16(z16[src])*A+B)
//  logits[n] += h[n] @ fcWl  (wave butterfly; lane holds column lane of h)
__global__ __launch_bounds__(256) void k_aggbn(
    const float* __restrict__ z, const unsigned short* __restrict__ z16,
    const float* __restrict__ stats_in, const float* __restrict__ gv,
    const float* __restrict__ bev,
    const int* __restrict__ offs, const int* __restrict__ csr,
    const float* __restrict__ fcWl, float* __restrict__ logits,
    float* __restrict__ vout, int N) {
  __shared__ float ABs[128];
  int tid = threadIdx.x;
  if (tid < 64) {
    float inv_n = 1.f / (float)N;
    float mu = stats_in[tid] * inv_n;
    float var = stats_in[64 + tid] * inv_n - mu * mu;
    float A = rsqrtf(var + BN_EPS) * gv[tid];
    ABs[tid] = A;
    ABs[64 + tid] = bev[tid] - mu * A;
  }
  __syncthreads();
  int gid = blockIdx.x * blockDim.x + tid;
  int wid = __builtin_amdgcn_readfirstlane(gid >> 6);
  int lane = tid & 63;
  if (wid >= N) return;
  float A = ABs[lane], B = ABs[64 + lane];
  float hs = fmaxf(z[(size_t)wid * 64 + lane] * A + B, 0.f);
  float acc = hs;
  int e0 = offs[wid], e1 = offs[wid + 1];
  int e = e0;
  for (; e + 8 <= e1; e += 8) {
    int s0 = csr[e], s1 = csr[e + 1], s2 = csr[e + 2], s3 = csr[e + 3];
    int s4 = csr[e + 4], s5 = csr[e + 5], s6 = csr[e + 6], s7 = csr[e + 7];
    float a0 = bf2f(z16[(size_t)s0 * 64 + lane]);
    float a1 = bf2f(z16[(size_t)s1 * 64 + lane]);
    float a2 = bf2f(z16[(size_t)s2 * 64 + lane]);
    float a3 = bf2f(z16[(size_t)s3 * 64 + lane]);
    float a4 = bf2f(z16[(size_t)s4 * 64 + lane]);
    float a5 = bf2f(z16[(size_t)s5 * 64 + lane]);
    float a6 = bf2f(z16[(size_t)s6 * 64 + lane]);
    float a7 = bf2f(z16[(size_t)s7 * 64 + lane]);
    a0 = fmaxf(a0 * A + B, 0.f);
    a1 = fmaxf(a1 * A + B, 0.f);
    a2 = fmaxf(a2 * A + B, 0.f);
    a3 = fmaxf(a3 * A + B, 0.f);
    a4 = fmaxf(a4 * A + B, 0.f);
    a5 = fmaxf(a5 * A + B, 0.f);
    a6 = fmaxf(a6 * A + B, 0.f);
    a7 = fmaxf(a7 * A + B, 0.f);
    acc += ((a0 + a1) + (a2 + a3)) + ((a4 + a5) + (a6 + a7));
  }
  for (; e < e1; e++) {
    float a = bf2f(z16[(size_t)csr[e] * 64 + lane]);
    acc += fmaxf(a * A + B, 0.f);
  }
  vout[(size_t)wid * 64 + lane] = acc;
  // JK head: logits[wid] += h @ fcWl; lane holds h column `lane`
  float red[10];
#pragma unroll
  for (int c = 0; c < 10; c++) {
    float v = hs * fcWl[lane * 10 + c];
#pragma unroll
    for (int m = 1; m <= 32; m <<= 1) v += __shfl_xor(v, m);
    red[c] = v;
  }
  if (lane < 10) logits[(size_t)wid * 10 + lane] += red[lane];
}

// LDS-tiled GEMM, 128 rows/block, 4x8 thread tile.
//  dobn=1: AB from stats_in/gv/bev prologue; BN+ReLU on A staging.
//  z16out != nullptr: also emit bf16 shadow of the output.
// Epilogue: column sum/sumsq -> atomicAdd stats_out[128]. In-place safe.
__global__ __launch_bounds__(256) void k_gemm2(
    const float* __restrict__ vin, float* __restrict__ zout,
    unsigned short* __restrict__ z16out, const float* __restrict__ W,
    const float* __restrict__ stats_in, const float* __restrict__ gv,
    const float* __restrict__ bev, int dobn,
    float* __restrict__ stats_out, int N) {
  __shared__ float As[128 * 68];
  __shared__ float Ws[64 * 68];
  __shared__ float ABs[128];
  int tid = threadIdx.x;
  int n0 = blockIdx.x * 128;
  if (dobn) {
    if (tid < 64) {
      float inv_n = 1.f / (float)N;
      float mu = stats_in[tid] * inv_n;
      float var = stats_in[64 + tid] * inv_n - mu * mu;
      float A = rsqrtf(var + BN_EPS) * gv[tid];
      ABs[tid] = A;
      ABs[64 + tid] = bev[tid] - mu * A;
    }
    __syncthreads();
  }
#pragma unroll
  for (int i = 0; i < 4; i++) {
    int g = tid + i * 256;
    int r = g >> 4, q = g & 15;
    float4 t = *(const float4*)(W + r * 64 + 4 * q);
    int base = r * 68 + 4 * q;
    Ws[base] = t.x; Ws[base + 1] = t.y; Ws[base + 2] = t.z; Ws[base + 3] = t.w;
  }
#pragma unroll
  for (int i = 0; i < 8; i++) {
    int g = tid + i * 256;
    int r = g >> 4, q = g & 15;
    int rn = n0 + r;
    float4 t = make_float4(0.f, 0.f, 0.f, 0.f);
    if (rn < N) t = *(const float4*)(vin + (size_t)rn * 64 + 4 * q);
    if (dobn) {
      float4 a = *(const float4*)(ABs + 4 * q);
      float4 b = *(const float4*)(ABs + 64 + 4 * q);
      t.x = fmaxf(t.x * a.x + b.x, 0.f);
      t.y = fmaxf(t.y * a.y + b.y, 0.f);
      t.z = fmaxf(t.z * a.z + b.z, 0.f);
      t.w = fmaxf(t.w * a.w + b.w, 0.f);
    }
    int base = r * 68 + 4 * q;
    As[base] = t.x; As[base + 1] = t.y; As[base + 2] = t.z; As[base + 3] = t.w;
  }
  __syncthreads();
  int tr = tid >> 3, tc = tid & 7;
  int ra = tr * 4;
  float acc[4][8];
#pragma unroll
  for (int i = 0; i < 4; i++)
#pragma unroll
    for (int j = 0; j < 8; j++) acc[i][j] = 0.f;
#pragma unroll 4
  for (int k = 0; k < 64; k++) {
    float av[4];
#pragma unroll
    for (int i = 0; i < 4; i++) av[i] = As[(ra + i) * 68 + k];
    const float* wk = &Ws[k * 68 + tc * 8];
    float4 w0 = *(const float4*)wk;
    float4 w1 = *(const float4*)(wk + 4);
    float wv[8] = {w0.x, w0.y, w0.z, w0.w, w1.x, w1.y, w1.z, w1.w};
#pragma unroll
    for (int i = 0; i < 4; i++)
#pragma unroll
      for (int j = 0; j < 8; j++) acc[i][j] += av[i] * wv[j];
  }
#pragma unroll
  for (int i = 0; i < 4; i++) {
    int rn = n0 + ra + i;
    if (rn < N) {
      float* zr = zout + (size_t)rn * 64 + tc * 8;
      *(float4*)zr = make_float4(acc[i][0], acc[i][1], acc[i][2], acc[i][3]);
      *(float4*)(zr + 4) = make_float4(acc[i][4], acc[i][5], acc[i][6], acc[i][7]);
      if (z16out) {
        unsigned short* zs = z16out + (size_t)rn * 64 + tc * 8;
        *(ushort4*)zs = make_ushort4(f2bf(acc[i][0]), f2bf(acc[i][1]),
                                     f2bf(acc[i][2]), f2bf(acc[i][3]));
        *(ushort4*)(zs + 4) = make_ushort4(f2bf(acc[i][4]), f2bf(acc[i][5]),
                                           f2bf(acc[i][6]), f2bf(acc[i][7]));
      }
    }
  }
  float cs[8], cq[8];
#pragma unroll
  for (int j = 0; j < 8; j++) {
    float s = 0.f, q = 0.f;
#pragma unroll
    for (int i = 0; i < 4; i++) {
      s += acc[i][j];
      q += acc[i][j] * acc[i][j];
    }
    cs[j] = s;
    cq[j] = q;
  }
#pragma unroll
  for (int m = 8; m <= 32; m <<= 1) {
#pragma unroll
    for (int j = 0; j < 8; j++) {
      cs[j] += __shfl_xor(cs[j], m);
      cq[j] += __shfl_xor(cq[j], m);
    }
  }
  __syncthreads();
  int w = tid >> 6;
  if ((tid & 63) < 8) {
    int c = tc * 8;
#pragma unroll
    for (int j = 0; j < 8; j++) {
      Ws[w * 128 + c + j] = cs[j];
      Ws[w * 128 + 64 + c + j] = cq[j];
    }
  }
  __syncthreads();
  if (tid < 64) {
    float a = Ws[tid] + Ws[128 + tid] + Ws[256 + tid] + Ws[384 + tid];
    float b = Ws[64 + tid] + Ws[192 + tid] + Ws[320 + tid] + Ws[448 + tid];
    atomicAdd(&stats_out[tid], a);
    atomicAdd(&stats_out[64 + tid], b);
  }
}

// final layer: h = relu(z*A+B); logits += h@fcW3; log_softmax -> out
__global__ __launch_bounds__(256) void k_head_final(
    const float* __restrict__ z,
    const float* __restrict__ stats_in, const float* __restrict__ gv,
    const float* __restrict__ bev, const float* __restrict__ fcWl,
    const float* __restrict__ logits, float* __restrict__ out, int N) {
  __shared__ float vs[256 * 17];
  __shared__ float ABs[128];
  int tid = threadIdx.x;
  if (tid < 64) {
    float inv_n = 1.f / (float)N;
    float mu = stats_in[tid] * inv_n;
    float var = stats_in[64 + tid] * inv_n - mu * mu;
    float A = rsqrtf(var + BN_EPS) * gv[tid];
    ABs[tid] = A;
    ABs[64 + tid] = bev[tid] - mu * A;
  }
  int n0 = blockIdx.x * 256;
  int n = n0 + tid;
  float acc[10];
#pragma unroll
  for (int c = 0; c < 10; c++) acc[c] = 0.f;
#pragma unroll 1
  for (int fb = 0; fb < 64; fb += 16) {
    __syncthreads();
#pragma unroll
    for (int g = 0; g < 4; g++) {
      int r = g * 64 + (tid >> 2);
      int q = tid & 3;
      int rn = n0 + r;
      float4 t = (rn < N) ? *(const float4*)(z + (size_t)rn * 64 + fb + 4 * q)
                          : make_float4(0.f, 0.f, 0.f, 0.f);
      int base = r * 17 + 4 * q;
      vs[base] = t.x;
      vs[base + 1] = t.y;
      vs[base + 2] = t.z;
      vs[base + 3] = t.w;
    }
    __syncthreads();
#pragma unroll
    for (int fc = 0; fc < 16; fc++) {
      int f = fb + fc;
      float val = fmaxf(vs[tid * 17 + fc] * ABs[f] + ABs[64 + f], 0.f);
      const float* wr = fcWl + f * 10;
#pragma unroll
      for (int c = 0; c < 10; c++) acc[c] += val * wr[c];
    }
  }
  if (n < N) {
    const float* lr = logits + (size_t)n * 10;
    float v[10];
    float m = -INFINITY;
#pragma unroll
    for (int c = 0; c < 10; c++) {
      v[c] = lr[c] + acc[c];
      m = fmaxf(m, v[c]);
    }
    float s = 0.f;
#pragma unroll
    for (int c = 0; c < 10; c++) s += expf(v[c] - m);
    float l = logf(s) + m;
    float* orow = out + (size_t)n * 10;
#pragma unroll
    for (int c = 0; c < 10; c++) orow[c] = v[c] - l;
  }
}

extern "C" void kernel_launch(void* const* d_in, const int* in_sizes, int n_in,
                              void* d_out, int out_size, void* d_ws, size_t ws_size,
                              hipStream_t stream) {
  const float* x = (const float*)d_in[0];
  const int* ei = (const int*)d_in[1];
  const float* W1 = (const float*)d_in[2];
  const float* g1 = (const float*)d_in[4];
  const float* be1 = (const float*)d_in[5];
  const float* W2 = (const float*)d_in[6];
  const float* gbn = (const float*)d_in[8];
  const float* bbn = (const float*)d_in[9];
  const float* fcW = (const float*)d_in[10];
  const float* fcb = (const float*)d_in[11];
  float* out = (float*)d_out;

  const int N = in_sizes[0] / 64;
  const int E = in_sizes[1] / 2;
  const int* src = ei;
  const int* dst = ei + E;

  char* ws = (char*)d_ws;
  size_t off = 0;
  auto alloc = [&](size_t bytes) -> void* {
    void* p = ws + off;
    off = (off + bytes + 255) & ~(size_t)255;
    return p;
  };
  float* stats = (float*)alloc(6 * 128 * 4);  // zeroed by k_scanblock2
  int* bpart = (int*)alloc((size_t)HBLK * NBKT * 4);
  int* bbase = (int*)alloc((NBKT + 1) * 4);
  int* bcur = (int*)alloc(NBKT * 4);
  int* offs = (int*)alloc(((size_t)NBKT * 512 + 1) * 4);
  int* csr = (int*)alloc((size_t)E * 4);
  float* zbuf = (float*)alloc((size_t)N * 64 * 4);
  float* logits = (float*)alloc((size_t)N * 10 * 4);
  unsigned short* x16 = (unsigned short*)alloc((size_t)N * 64 * 2);
  unsigned short* z16 = (unsigned short*)alloc((size_t)N * 64 * 2);
  float* vbuf = (float*)alloc((size_t)N * 64 * 4);
  int2* ep = (int2*)vbuf;  // alias: ep dead before vbuf first written
  (void)ws_size;
  (void)n_in;
  (void)out_size;

  int nb = (N + 255) / 256;
  int gb = (N + 127) / 128;
  int ab = (N * 64 + 255) / 256;
  int nparts = (E + PCHUNK - 1) / PCHUNK;
  k_buckethist<<<HBLK, 256, 0, stream>>>(dst, bpart, E);
  k_scanblock2<<<1, 256, 0, stream>>>(bpart, bbase, bcur, stats, E);
  k_part_head<<<nparts + nb, 256, 0, stream>>>(src, dst, bcur, ep, E, nparts, x,
                                               fcW, fcb, logits, x16, N);
  k_bucketsort<<<NBKT, 256, 0, stream>>>(ep, bbase, offs, csr);

  for (int l = 0; l < 3; l++) {
    float* st1 = stats + (2 * l) * 128;
    float* st2 = stats + (2 * l + 1) * 128;
    if (l == 0) {
      k_agg<<<ab, 256, 0, stream>>>(x, x16, offs, csr, vbuf, N);
    } else {
      float* st2p = stats + (2 * (l - 1) + 1) * 128;
      k_aggbn<<<ab, 256, 0, stream>>>(zbuf, z16, st2p, gbn + (l - 1) * 64,
                                      bbn + (l - 1) * 64, offs, csr,
                                      fcW + l * 640, logits, vbuf, N);
    }
    k_gemm2<<<gb, 256, 0, stream>>>(vbuf, zbuf, nullptr, W1 + l * 4096, nullptr,
                                    nullptr, nullptr, 0, st1, N);
    unsigned short* zs = (l < 2) ? z16 : nullptr;
    k_gemm2<<<gb, 256, 0, stream>>>(zbuf, zbuf, zs, W2 + l * 4096, st1,
                                    g1 + l * 64, be1 + l * 64, 1, st2, N);
  }
  k_head_final<<<nb, 256, 0, stream>>>(zbuf, stats + 5 * 128, gbn + 128, bbn + 128,
                                       fcW + 3 * 640, logits, out, N);
}

// Round 11
// 594.023 us; speedup vs baseline: 9.6169x; 1.0458x over previous
//
#include <hip/hip_runtime.h>
#include <math.h>

// GIN: N=100000 nodes, E=1600000 edges, F=D=64, L=3 layers, C=10 classes.
// R11: fix R10's aggbn regression (8-deep unroll fell below the random-access
// HBM ceiling; 91.6us vs plain agg 47us): 16-deep unroll restored, fcWl in
// LDS, self term from bf16 shadow (drops fp32 z read). Launch nodes 14->13:
// hist+scan kernels replaced by fixed-capacity buckets (BCAP=12288, direct
// atomicAdd on bcur; bcur via 1KB memset node; stats zeroed in bucketsort).
// PCHUNK 8192->4096 for more partition parallelism.

#define BN_EPS 1e-5f
#define NBKT 256     // dst buckets (dst>>9)
#define BCAP 12288   // per-bucket edge capacity (mean 8163, +45 sigma)
#define PCHUNK 4096  // edges per partition block

__device__ __forceinline__ float bf2f(unsigned short u) {
  return __uint_as_float(((unsigned int)u) << 16);
}
__device__ __forceinline__ unsigned short f2bf(float x) {  // RNE
  unsigned int b = __float_as_uint(x);
  return (unsigned short)((b + 0x7FFFu + ((b >> 16) & 1u)) >> 16);
}

// ---------- CSR build ----------

// combined dispatch: blocks [0,nparts) partition edges into fixed-capacity
// dst-buckets (direct atomicAdd on bcur); rest do head_init (+x16 shadow).
__global__ __launch_bounds__(256) void k_part_head(
    const int* __restrict__ src, const int* __restrict__ dst,
    int* __restrict__ bcur, int2* __restrict__ ep, int E, int nparts,
    const float* __restrict__ x, const float* __restrict__ fcW0,
    const float* __restrict__ fcb, float* __restrict__ logits,
    unsigned short* __restrict__ x16, int N) {
  __shared__ char smem[256 * 17 * 4];
  int tid = threadIdx.x;
  if ((int)blockIdx.x < nparts) {
    int* lh = (int*)smem;
    int* lbase = lh + NBKT;
    int* lcur = lh + 2 * NBKT;
    int base = blockIdx.x * PCHUNK;
    int end = min(base + PCHUNK, E);
    lh[tid] = 0;
    lcur[tid] = 0;
    __syncthreads();
    for (int e = base + tid; e < end; e += 256) atomicAdd(&lh[dst[e] >> 9], 1);
    __syncthreads();
    int c = lh[tid];
    lbase[tid] = c ? (tid * BCAP + atomicAdd(&bcur[tid], c)) : 0;
    __syncthreads();
    for (int e = base + tid; e < end; e += 256) {
      int d = dst[e];
      int b = d >> 9;
      int r = atomicAdd(&lcur[b], 1);
      ep[lbase[b] + r] = make_int2(src[e], d);
    }
  } else {
    float* vs = (float*)smem;
    int n0 = (blockIdx.x - nparts) * 256;
    int n = n0 + tid;
    float acc[10];
#pragma unroll
    for (int c = 0; c < 10; c++) acc[c] = 0.f;
#pragma unroll 1
    for (int fb = 0; fb < 64; fb += 16) {
      __syncthreads();
#pragma unroll
      for (int g = 0; g < 4; g++) {
        int r = g * 64 + (tid >> 2);
        int q = tid & 3;
        int rn = n0 + r;
        float4 t = make_float4(0.f, 0.f, 0.f, 0.f);
        if (rn < N) {
          t = *(const float4*)(x + (size_t)rn * 64 + fb + 4 * q);
          *(ushort4*)(x16 + (size_t)rn * 64 + fb + 4 * q) =
              make_ushort4(f2bf(t.x), f2bf(t.y), f2bf(t.z), f2bf(t.w));
        }
        int base = r * 17 + 4 * q;
        vs[base] = t.x;
        vs[base + 1] = t.y;
        vs[base + 2] = t.z;
        vs[base + 3] = t.w;
      }
      __syncthreads();
      for (int fc = 0; fc < 16; fc++) {
        int f = fb + fc;
        float vf = vs[tid * 17 + fc];
        const float* wr = fcW0 + f * 10;
#pragma unroll
        for (int c = 0; c < 10; c++) acc[c] += vf * wr[c];
      }
    }
    if (n < N) {
      float* lr = logits + (size_t)n * 10;
#pragma unroll
      for (int c = 0; c < 10; c++)
        lr[c] = acc[c] + (fcb[c] + fcb[10 + c] + fcb[20 + c] + fcb[30 + c]);
    }
  }
}

// per-bucket LDS counting sort (bucket b edges: ep[b*BCAP, b*BCAP+bcur[b])).
// Emits offs (csr start per node), bend[b] (end of bucket's last node), csr.
// Block 0 also zeroes stats[768].
__global__ __launch_bounds__(256) void k_bucketsort(
    const int2* __restrict__ ep, const int* __restrict__ bcur,
    int* __restrict__ offs, int* __restrict__ bend, int* __restrict__ csr,
    float* __restrict__ stats) {
  __shared__ int cnt[512];
  __shared__ int ts[256];
  __shared__ int cur[512];
  int t = threadIdx.x;
  int b = blockIdx.x;
  if (b == 0) {
    for (int i = t; i < 768; i += 256) stats[i] = 0.f;
  }
  int lo = b * BCAP;
  int hi = lo + bcur[b];
  cnt[t] = 0;
  cnt[t + 256] = 0;
  __syncthreads();
  for (int e = lo + t; e < hi; e += 256) atomicAdd(&cnt[ep[e].y & 511], 1);
  __syncthreads();
  int c0 = cnt[2 * t], c1 = cnt[2 * t + 1];
  int s = c0 + c1;
  ts[t] = s;
  __syncthreads();
  for (int o = 1; o < 256; o <<= 1) {
    int add = (t >= o) ? ts[t - o] : 0;
    __syncthreads();
    ts[t] += add;
    __syncthreads();
  }
  int excl = ts[t] - s;
  cur[2 * t] = excl;
  cur[2 * t + 1] = excl + c0;
  int n0 = b << 9;
  offs[n0 + 2 * t] = lo + excl;
  offs[n0 + 2 * t + 1] = lo + excl + c0;
  if (t == 255) bend[b] = lo + ts[255];
  __syncthreads();
  for (int e = lo + t; e < hi; e += 256) {
    int2 p = ep[e];
    int pos = atomicAdd(&cur[p.y & 511], 1);
    csr[lo + pos] = p.x;
  }
}

// ---------- compute ----------

// 16-deep bf16 neighbor gather (no BN): sum of h16[src]
__device__ __forceinline__ float gather_plain(
    const unsigned short* __restrict__ h16, const int* __restrict__ csr,
    int e0, int e1, int lane) {
  float acc = 0.f;
  int e = e0;
  for (; e + 16 <= e1; e += 16) {
    int s0 = csr[e], s1 = csr[e + 1], s2 = csr[e + 2], s3 = csr[e + 3];
    int s4 = csr[e + 4], s5 = csr[e + 5], s6 = csr[e + 6], s7 = csr[e + 7];
    int s8 = csr[e + 8], s9 = csr[e + 9], sa = csr[e + 10], sb = csr[e + 11];
    int sc = csr[e + 12], sd = csr[e + 13], se = csr[e + 14], sf = csr[e + 15];
    float a0 = bf2f(h16[(size_t)s0 * 64 + lane]);
    float a1 = bf2f(h16[(size_t)s1 * 64 + lane]);
    float a2 = bf2f(h16[(size_t)s2 * 64 + lane]);
    float a3 = bf2f(h16[(size_t)s3 * 64 + lane]);
    float a4 = bf2f(h16[(size_t)s4 * 64 + lane]);
    float a5 = bf2f(h16[(size_t)s5 * 64 + lane]);
    float a6 = bf2f(h16[(size_t)s6 * 64 + lane]);
    float a7 = bf2f(h16[(size_t)s7 * 64 + lane]);
    float a8 = bf2f(h16[(size_t)s8 * 64 + lane]);
    float a9 = bf2f(h16[(size_t)s9 * 64 + lane]);
    float aa = bf2f(h16[(size_t)sa * 64 + lane]);
    float ab = bf2f(h16[(size_t)sb * 64 + lane]);
    float ac = bf2f(h16[(size_t)sc * 64 + lane]);
    float ad = bf2f(h16[(size_t)sd * 64 + lane]);
    float ae = bf2f(h16[(size_t)se * 64 + lane]);
    float af = bf2f(h16[(size_t)sf * 64 + lane]);
    acc += (((a0 + a1) + (a2 + a3)) + ((a4 + a5) + (a6 + a7))) +
           (((a8 + a9) + (aa + ab)) + ((ac + ad) + (ae + af)));
  }
  for (; e + 4 <= e1; e += 4) {
    int s0 = csr[e], s1 = csr[e + 1], s2 = csr[e + 2], s3 = csr[e + 3];
    float a0 = bf2f(h16[(size_t)s0 * 64 + lane]);
    float a1 = bf2f(h16[(size_t)s1 * 64 + lane]);
    float a2 = bf2f(h16[(size_t)s2 * 64 + lane]);
    float a3 = bf2f(h16[(size_t)s3 * 64 + lane]);
    acc += (a0 + a1) + (a2 + a3);
  }
  for (; e < e1; e++) acc += bf2f(h16[(size_t)csr[e] * 64 + lane]);
  return acc;
}

// layer-0 aggregation: v[n] = x16[n] + sum x16[src]  (all bf16 reads)
__global__ __launch_bounds__(256) void k_agg(
    const unsigned short* __restrict__ h16, const int* __restrict__ offs,
    const int* __restrict__ bend, const int* __restrict__ csr,
    float* __restrict__ vout, int N) {
  int gid = blockIdx.x * blockDim.x + threadIdx.x;
  int wid = __builtin_amdgcn_readfirstlane(gid >> 6);
  int lane = threadIdx.x & 63;
  if (wid >= N) return;
  int e0 = offs[wid];
  int e1 = ((wid & 511) == 511) ? bend[wid >> 9] : offs[wid + 1];
  float acc = bf2f(h16[(size_t)wid * 64 + lane]) +
              gather_plain(h16, csr, e0, e1, lane);
  vout[(size_t)wid * 64 + lane] = acc;
}

// fused BN+ReLU aggregation + JK head for layers 1..L-1 (16-deep unroll):
//  h = relu(bf16(z16)*A+B); v[n] = h[n] + sum h[src]; logits[n] += h[n]@fcWl
__global__ __launch_bounds__(256) void k_aggbn(
    const unsigned short* __restrict__ z16,
    const float* __restrict__ stats_in, const float* __restrict__ gv,
    const float* __restrict__ bev,
    const int* __restrict__ offs, const int* __restrict__ bend,
    const int* __restrict__ csr, const float* __restrict__ fcWl,
    float* __restrict__ logits, float* __restrict__ vout, int N) {
  __shared__ float ABs[128];
  __shared__ float fw[640];
  int tid = threadIdx.x;
  if (tid < 64) {
    float inv_n = 1.f / (float)N;
    float mu = stats_in[tid] * inv_n;
    float var = stats_in[64 + tid] * inv_n - mu * mu;
    float A = rsqrtf(var + BN_EPS) * gv[tid];
    ABs[tid] = A;
    ABs[64 + tid] = bev[tid] - mu * A;
  }
  for (int i = tid; i < 640; i += 256) fw[i] = fcWl[i];
  __syncthreads();
  int gid = blockIdx.x * blockDim.x + tid;
  int wid = __builtin_amdgcn_readfirstlane(gid >> 6);
  int lane = tid & 63;
  if (wid >= N) return;
  float A = ABs[lane], B = ABs[64 + lane];
  float hs = fmaxf(bf2f(z16[(size_t)wid * 64 + lane]) * A + B, 0.f);
  float acc = hs;
  int e0 = offs[wid];
  int e1 = ((wid & 511) == 511) ? bend[wid >> 9] : offs[wid + 1];
  int e = e0;
  for (; e + 16 <= e1; e += 16) {
    int s0 = csr[e], s1 = csr[e + 1], s2 = csr[e + 2], s3 = csr[e + 3];
    int s4 = csr[e + 4], s5 = csr[e + 5], s6 = csr[e + 6], s7 = csr[e + 7];
    int s8 = csr[e + 8], s9 = csr[e + 9], sa = csr[e + 10], sb = csr[e + 11];
    int sc = csr[e + 12], sd = csr[e + 13], se = csr[e + 14], sf = csr[e + 15];
    float a0 = bf2f(z16[(size_t)s0 * 64 + lane]);
    float a1 = bf2f(z16[(size_t)s1 * 64 + lane]);
    float a2 = bf2f(z16[(size_t)s2 * 64 + lane]);
    float a3 = bf2f(z16[(size_t)s3 * 64 + lane]);
    float a4 = bf2f(z16[(size_t)s4 * 64 + lane]);
    float a5 = bf2f(z16[(size_t)s5 * 64 + lane]);
    float a6 = bf2f(z16[(size_t)s6 * 64 + lane]);
    float a7 = bf2f(z16[(size_t)s7 * 64 + lane]);
    float a8 = bf2f(z16[(size_t)s8 * 64 + lane]);
    float a9 = bf2f(z16[(size_t)s9 * 64 + lane]);
    float aa = bf2f(z16[(size_t)sa * 64 + lane]);
    float ab = bf2f(z16[(size_t)sb * 64 + lane]);
    float ac = bf2f(z16[(size_t)sc * 64 + lane]);
    float ad = bf2f(z16[(size_t)sd * 64 + lane]);
    float ae = bf2f(z16[(size_t)se * 64 + lane]);
    float af = bf2f(z16[(size_t)sf * 64 + lane]);
    a0 = fmaxf(a0 * A + B, 0.f); a1 = fmaxf(a1 * A + B, 0.f);
    a2 = fmaxf(a2 * A + B, 0.f); a3 = fmaxf(a3 * A + B, 0.f);
    a4 = fmaxf(a4 * A + B, 0.f); a5 = fmaxf(a5 * A + B, 0.f);
    a6 = fmaxf(a6 * A + B, 0.f); a7 = fmaxf(a7 * A + B, 0.f);
    a8 = fmaxf(a8 * A + B, 0.f); a9 = fmaxf(a9 * A + B, 0.f);
    aa = fmaxf(aa * A + B, 0.f); ab = fmaxf(ab * A + B, 0.f);
    ac = fmaxf(ac * A + B, 0.f); ad = fmaxf(ad * A + B, 0.f);
    ae = fmaxf(ae * A + B, 0.f); af = fmaxf(af * A + B, 0.f);
    acc += (((a0 + a1) + (a2 + a3)) + ((a4 + a5) + (a6 + a7))) +
           (((a8 + a9) + (aa + ab)) + ((ac + ad) + (ae + af)));
  }
  for (; e + 4 <= e1; e += 4) {
    int s0 = csr[e], s1 = csr[e + 1], s2 = csr[e + 2], s3 = csr[e + 3];
    float a0 = bf2f(z16[(size_t)s0 * 64 + lane]);
    float a1 = bf2f(z16[(size_t)s1 * 64 + lane]);
    float a2 = bf2f(z16[(size_t)s2 * 64 + lane]);
    float a3 = bf2f(z16[(size_t)s3 * 64 + lane]);
    a0 = fmaxf(a0 * A + B, 0.f); a1 = fmaxf(a1 * A + B, 0.f);
    a2 = fmaxf(a2 * A + B, 0.f); a3 = fmaxf(a3 * A + B, 0.f);
    acc += (a0 + a1) + (a2 + a3);
  }
  for (; e < e1; e++) {
    float a = bf2f(z16[(size_t)csr[e] * 64 + lane]);
    acc += fmaxf(a * A + B, 0.f);
  }
  vout[(size_t)wid * 64 + lane] = acc;
  // JK head: logits[wid] += h @ fcWl (lane holds h column `lane`)
  float red[10];
#pragma unroll
  for (int c = 0; c < 10; c++) {
    float v = hs * fw[lane * 10 + c];
#pragma unroll
    for (int m = 1; m <= 32; m <<= 1) v += __shfl_xor(v, m);
    red[c] = v;
  }
  if (lane < 10) logits[(size_t)wid * 10 + lane] += red[lane];
}

// LDS-tiled GEMM, 128 rows/block, 4x8 thread tile.
//  dobn=1: AB from stats_in/gv/bev prologue; BN+ReLU on A staging.
//  z16out != nullptr: also emit bf16 shadow of output.
// Epilogue: column sum/sumsq -> atomicAdd stats_out[128]. In-place safe.
__global__ __launch_bounds__(256) void k_gemm2(
    const float* __restrict__ vin, float* __restrict__ zout,
    unsigned short* __restrict__ z16out, const float* __restrict__ W,
    const float* __restrict__ stats_in, const float* __restrict__ gv,
    const float* __restrict__ bev, int dobn,
    float* __restrict__ stats_out, int N) {
  __shared__ float As[128 * 68];
  __shared__ float Ws[64 * 68];
  __shared__ float ABs[128];
  int tid = threadIdx.x;
  int n0 = blockIdx.x * 128;
  if (dobn) {
    if (tid < 64) {
      float inv_n = 1.f / (float)N;
      float mu = stats_in[tid] * inv_n;
      float var = stats_in[64 + tid] * inv_n - mu * mu;
      float A = rsqrtf(var + BN_EPS) * gv[tid];
      ABs[tid] = A;
      ABs[64 + tid] = bev[tid] - mu * A;
    }
    __syncthreads();
  }
#pragma unroll
  for (int i = 0; i < 4; i++) {
    int g = tid + i * 256;
    int r = g >> 4, q = g & 15;
    float4 t = *(const float4*)(W + r * 64 + 4 * q);
    int base = r * 68 + 4 * q;
    Ws[base] = t.x; Ws[base + 1] = t.y; Ws[base + 2] = t.z; Ws[base + 3] = t.w;
  }
#pragma unroll
  for (int i = 0; i < 8; i++) {
    int g = tid + i * 256;
    int r = g >> 4, q = g & 15;
    int rn = n0 + r;
    float4 t = make_float4(0.f, 0.f, 0.f, 0.f);
    if (rn < N) t = *(const float4*)(vin + (size_t)rn * 64 + 4 * q);
    if (dobn) {
      float4 a = *(const float4*)(ABs + 4 * q);
      float4 b = *(const float4*)(ABs + 64 + 4 * q);
      t.x = fmaxf(t.x * a.x + b.x, 0.f);
      t.y = fmaxf(t.y * a.y + b.y, 0.f);
      t.z = fmaxf(t.z * a.z + b.z, 0.f);
      t.w = fmaxf(t.w * a.w + b.w, 0.f);
    }
    int base = r * 68 + 4 * q;
    As[base] = t.x; As[base + 1] = t.y; As[base + 2] = t.z; As[base + 3] = t.w;
  }
  __syncthreads();
  int tr = tid >> 3, tc = tid & 7;
  int ra = tr * 4;
  float acc[4][8];
#pragma unroll
  for (int i = 0; i < 4; i++)
#pragma unroll
    for (int j = 0; j < 8; j++) acc[i][j] = 0.f;
#pragma unroll 4
  for (int k = 0; k < 64; k++) {
    float av[4];
#pragma unroll
    for (int i = 0; i < 4; i++) av[i] = As[(ra + i) * 68 + k];
    const float* wk = &Ws[k * 68 + tc * 8];
    float4 w0 = *(const float4*)wk;
    float4 w1 = *(const float4*)(wk + 4);
    float wv[8] = {w0.x, w0.y, w0.z, w0.w, w1.x, w1.y, w1.z, w1.w};
#pragma unroll
    for (int i = 0; i < 4; i++)
#pragma unroll
      for (int j = 0; j < 8; j++) acc[i][j] += av[i] * wv[j];
  }
#pragma unroll
  for (int i = 0; i < 4; i++) {
    int rn = n0 + ra + i;
    if (rn < N) {
      float* zr = zout + (size_t)rn * 64 + tc * 8;
      *(float4*)zr = make_float4(acc[i][0], acc[i][1], acc[i][2], acc[i][3]);
      *(float4*)(zr + 4) = make_float4(acc[i][4], acc[i][5], acc[i][6], acc[i][7]);
      if (z16out) {
        unsigned short* zs = z16out + (size_t)rn * 64 + tc * 8;
        *(ushort4*)zs = make_ushort4(f2bf(acc[i][0]), f2bf(acc[i][1]),
                                     f2bf(acc[i][2]), f2bf(acc[i][3]));
        *(ushort4*)(zs + 4) = make_ushort4(f2bf(acc[i][4]), f2bf(acc[i][5]),
                                           f2bf(acc[i][6]), f2bf(acc[i][7]));
      }
    }
  }
  float cs[8], cq[8];
#pragma unroll
  for (int j = 0; j < 8; j++) {
    float s = 0.f, q = 0.f;
#pragma unroll
    for (int i = 0; i < 4; i++) {
      s += acc[i][j];
      q += acc[i][j] * acc[i][j];
    }
    cs[j] = s;
    cq[j] = q;
  }
#pragma unroll
  for (int m = 8; m <= 32; m <<= 1) {
#pragma unroll
    for (int j = 0; j < 8; j++) {
      cs[j] += __shfl_xor(cs[j], m);
      cq[j] += __shfl_xor(cq[j], m);
    }
  }
  __syncthreads();
  int w = tid >> 6;
  if ((tid & 63) < 8) {
    int c = tc * 8;
#pragma unroll
    for (int j = 0; j < 8; j++) {
      Ws[w * 128 + c + j] = cs[j];
      Ws[w * 128 + 64 + c + j] = cq[j];
    }
  }
  __syncthreads();
  if (tid < 64) {
    float a = Ws[tid] + Ws[128 + tid] + Ws[256 + tid] + Ws[384 + tid];
    float b = Ws[64 + tid] + Ws[192 + tid] + Ws[320 + tid] + Ws[448 + tid];
    atomicAdd(&stats_out[tid], a);
    atomicAdd(&stats_out[64 + tid], b);
  }
}

// final layer: h = relu(z*A+B); logits += h@fcW3; log_softmax -> out
__global__ __launch_bounds__(256) void k_head_final(
    const float* __restrict__ z,
    const float* __restrict__ stats_in, const float* __restrict__ gv,
    const float* __restrict__ bev, const float* __restrict__ fcWl,
    const float* __restrict__ logits, float* __restrict__ out, int N) {
  __shared__ float vs[256 * 17];
  __shared__ float ABs[128];
  int tid = threadIdx.x;
  if (tid < 64) {
    float inv_n = 1.f / (float)N;
    float mu = stats_in[tid] * inv_n;
    float var = stats_in[64 + tid] * inv_n - mu * mu;
    float A = rsqrtf(var + BN_EPS) * gv[tid];
    ABs[tid] = A;
    ABs[64 + tid] = bev[tid] - mu * A;
  }
  int n0 = blockIdx.x * 256;
  int n = n0 + tid;
  float acc[10];
#pragma unroll
  for (int c = 0; c < 10; c++) acc[c] = 0.f;
#pragma unroll 1
  for (int fb = 0; fb < 64; fb += 16) {
    __syncthreads();
#pragma unroll
    for (int g = 0; g < 4; g++) {
      int r = g * 64 + (tid >> 2);
      int q = tid & 3;
      int rn = n0 + r;
      float4 t = (rn < N) ? *(const float4*)(z + (size_t)rn * 64 + fb + 4 * q)
                          : make_float4(0.f, 0.f, 0.f, 0.f);
      int base = r * 17 + 4 * q;
      vs[base] = t.x;
      vs[base + 1] = t.y;
      vs[base + 2] = t.z;
      vs[base + 3] = t.w;
    }
    __syncthreads();
#pragma unroll
    for (int fc = 0; fc < 16; fc++) {
      int f = fb + fc;
      float val = fmaxf(vs[tid * 17 + fc] * ABs[f] + ABs[64 + f], 0.f);
      const float* wr = fcWl + f * 10;
#pragma unroll
      for (int c = 0; c < 10; c++) acc[c] += val * wr[c];
    }
  }
  if (n < N) {
    const float* lr = logits + (size_t)n * 10;
    float v[10];
    float m = -INFINITY;
#pragma unroll
    for (int c = 0; c < 10; c++) {
      v[c] = lr[c] + acc[c];
      m = fmaxf(m, v[c]);
    }
    float s = 0.f;
#pragma unroll
    for (int c = 0; c < 10; c++) s += expf(v[c] - m);
    float l = logf(s) + m;
    float* orow = out + (size_t)n * 10;
#pragma unroll
    for (int c = 0; c < 10; c++) orow[c] = v[c] - l;
  }
}

extern "C" void kernel_launch(void* const* d_in, const int* in_sizes, int n_in,
                              void* d_out, int out_size, void* d_ws, size_t ws_size,
                              hipStream_t stream) {
  const float* x = (const float*)d_in[0];
  const int* ei = (const int*)d_in[1];
  const float* W1 = (const float*)d_in[2];
  const float* g1 = (const float*)d_in[4];
  const float* be1 = (const float*)d_in[5];
  const float* W2 = (const float*)d_in[6];
  const float* gbn = (const float*)d_in[8];
  const float* bbn = (const float*)d_in[9];
  const float* fcW = (const float*)d_in[10];
  const float* fcb = (const float*)d_in[11];
  float* out = (float*)d_out;

  const int N = in_sizes[0] / 64;
  const int E = in_sizes[1] / 2;
  const int* src = ei;
  const int* dst = ei + E;

  char* ws = (char*)d_ws;
  size_t off = 0;
  auto alloc = [&](size_t bytes) -> void* {
    void* p = ws + off;
    off = (off + bytes + 255) & ~(size_t)255;
    return p;
  };
  int* bcur = (int*)alloc(NBKT * 4);          // zeroed by memset node
  float* stats = (float*)alloc(6 * 128 * 4);  // zeroed by bucketsort blk 0
  int* offs = (int*)alloc((size_t)NBKT * 512 * 4);
  int* bend = (int*)alloc(NBKT * 4);
  int* csr = (int*)alloc((size_t)NBKT * BCAP * 4);
  float* zbuf = (float*)alloc((size_t)N * 64 * 4);
  float* logits = (float*)alloc((size_t)N * 10 * 4);
  unsigned short* x16 = (unsigned short*)alloc((size_t)N * 64 * 2);
  unsigned short* z16 = (unsigned short*)alloc((size_t)N * 64 * 2);
  float* vbuf = (float*)alloc((size_t)N * 64 * 4);
  int2* ep = (int2*)alloc((size_t)NBKT * BCAP * 8);
  (void)ws_size;
  (void)n_in;
  (void)out_size;

  int nb = (N + 255) / 256;
  int gb = (N + 127) / 128;
  int ab = (N * 64 + 255) / 256;
  int nparts = (E + PCHUNK - 1) / PCHUNK;
  hipMemsetAsync(bcur, 0, NBKT * 4, stream);
  k_part_head<<<nparts + nb, 256, 0, stream>>>(src, dst, bcur, ep, E, nparts, x,
                                               fcW, fcb, logits, x16, N);
  k_bucketsort<<<NBKT, 256, 0, stream>>>(ep, bcur, offs, bend, csr, stats);

  for (int l = 0; l < 3; l++) {
    float* st1 = stats + (2 * l) * 128;
    float* st2 = stats + (2 * l + 1) * 128;
    if (l == 0) {
      k_agg<<<ab, 256, 0, stream>>>(x16, offs, bend, csr, vbuf, N);
    } else {
      float* st2p = stats + (2 * (l - 1) + 1) * 128;
      k_aggbn<<<ab, 256, 0, stream>>>(z16, st2p, gbn + (l - 1) * 64,
                                      bbn + (l - 1) * 64, offs, bend, csr,
                                      fcW + l * 640, logits, vbuf, N);
    }
    k_gemm2<<<gb, 256, 0, stream>>>(vbuf, zbuf, nullptr, W1 + l * 4096, nullptr,
                                    nullptr, nullptr, 0, st1, N);
    unsigned short* zs = (l < 2) ? z16 : nullptr;
    k_gemm2<<<gb, 256, 0, stream>>>(zbuf, zbuf, zs, W2 + l * 4096, st1,
                                    g1 + l * 64, be1 + l * 64, 1, st2, N);
  }
  k_head_final<<<nb, 256, 0, stream>>>(zbuf, stats + 5 * 128, gbn + 128, bbn + 128,
                                       fcW + 3 * 640, logits, out, N);
}

// Round 12
// 546.952 us; speedup vs baseline: 10.4446x; 1.0861x over previous
//
#include <hip/hip_runtime.h>
#include <math.h>

// GIN: N=100000 nodes, E=1600000 edges, F=D=64, L=3 layers, C=10 classes.
// R12: aggbn is latency-bound per node (R11: FETCH -10% with no time change).
// The JK-head butterfly (60 dependent shuffles) + logits RMW (~L2 round trip)
// doubled the per-node critical path (47->94us vs plain agg). Fix: GEMM2
// writes per-layer z2 buffers; aggbn = BN+ReLU gather only; all three JK
// heads computed in one final kernel (k_head_final3) that re-reads z2_l
// coalesced (77MB ~= +12us). Launches unchanged (13).

#define BN_EPS 1e-5f
#define NBKT 256     // dst buckets (dst>>9)
#define BCAP 12288   // per-bucket edge capacity (mean 8163, +45 sigma)
#define PCHUNK 4096  // edges per partition block

__device__ __forceinline__ float bf2f(unsigned short u) {
  return __uint_as_float(((unsigned int)u) << 16);
}
__device__ __forceinline__ unsigned short f2bf(float x) {  // RNE
  unsigned int b = __float_as_uint(x);
  return (unsigned short)((b + 0x7FFFu + ((b >> 16) & 1u)) >> 16);
}

// ---------- CSR build ----------

// combined dispatch: blocks [0,nparts) partition edges into fixed-capacity
// dst-buckets (direct atomicAdd on bcur); rest do head_init (+x16 shadow).
__global__ __launch_bounds__(256) void k_part_head(
    const int* __restrict__ src, const int* __restrict__ dst,
    int* __restrict__ bcur, int2* __restrict__ ep, int E, int nparts,
    const float* __restrict__ x, const float* __restrict__ fcW0,
    const float* __restrict__ fcb, float* __restrict__ logits,
    unsigned short* __restrict__ x16, int N) {
  __shared__ char smem[256 * 17 * 4];
  int tid = threadIdx.x;
  if ((int)blockIdx.x < nparts) {
    int* lh = (int*)smem;
    int* lbase = lh + NBKT;
    int* lcur = lh + 2 * NBKT;
    int base = blockIdx.x * PCHUNK;
    int end = min(base + PCHUNK, E);
    lh[tid] = 0;
    lcur[tid] = 0;
    __syncthreads();
    for (int e = base + tid; e < end; e += 256) atomicAdd(&lh[dst[e] >> 9], 1);
    __syncthreads();
    int c = lh[tid];
    lbase[tid] = c ? (tid * BCAP + atomicAdd(&bcur[tid], c)) : 0;
    __syncthreads();
    for (int e = base + tid; e < end; e += 256) {
      int d = dst[e];
      int b = d >> 9;
      int r = atomicAdd(&lcur[b], 1);
      ep[lbase[b] + r] = make_int2(src[e], d);
    }
  } else {
    float* vs = (float*)smem;
    int n0 = (blockIdx.x - nparts) * 256;
    int n = n0 + tid;
    float acc[10];
#pragma unroll
    for (int c = 0; c < 10; c++) acc[c] = 0.f;
#pragma unroll 1
    for (int fb = 0; fb < 64; fb += 16) {
      __syncthreads();
#pragma unroll
      for (int g = 0; g < 4; g++) {
        int r = g * 64 + (tid >> 2);
        int q = tid & 3;
        int rn = n0 + r;
        float4 t = make_float4(0.f, 0.f, 0.f, 0.f);
        if (rn < N) {
          t = *(const float4*)(x + (size_t)rn * 64 + fb + 4 * q);
          *(ushort4*)(x16 + (size_t)rn * 64 + fb + 4 * q) =
              make_ushort4(f2bf(t.x), f2bf(t.y), f2bf(t.z), f2bf(t.w));
        }
        int base = r * 17 + 4 * q;
        vs[base] = t.x;
        vs[base + 1] = t.y;
        vs[base + 2] = t.z;
        vs[base + 3] = t.w;
      }
      __syncthreads();
      for (int fc = 0; fc < 16; fc++) {
        int f = fb + fc;
        float vf = vs[tid * 17 + fc];
        const float* wr = fcW0 + f * 10;
#pragma unroll
        for (int c = 0; c < 10; c++) acc[c] += vf * wr[c];
      }
    }
    if (n < N) {
      float* lr = logits + (size_t)n * 10;
#pragma unroll
      for (int c = 0; c < 10; c++)
        lr[c] = acc[c] + (fcb[c] + fcb[10 + c] + fcb[20 + c] + fcb[30 + c]);
    }
  }
}

// per-bucket LDS counting sort (bucket b edges: ep[b*BCAP, b*BCAP+bcur[b])).
// Emits offs (csr start per node), bend[b], csr. Block 0 zeroes stats[768].
__global__ __launch_bounds__(256) void k_bucketsort(
    const int2* __restrict__ ep, const int* __restrict__ bcur,
    int* __restrict__ offs, int* __restrict__ bend, int* __restrict__ csr,
    float* __restrict__ stats) {
  __shared__ int cnt[512];
  __shared__ int ts[256];
  __shared__ int cur[512];
  int t = threadIdx.x;
  int b = blockIdx.x;
  if (b == 0) {
    for (int i = t; i < 768; i += 256) stats[i] = 0.f;
  }
  int lo = b * BCAP;
  int hi = lo + bcur[b];
  cnt[t] = 0;
  cnt[t + 256] = 0;
  __syncthreads();
  for (int e = lo + t; e < hi; e += 256) atomicAdd(&cnt[ep[e].y & 511], 1);
  __syncthreads();
  int c0 = cnt[2 * t], c1 = cnt[2 * t + 1];
  int s = c0 + c1;
  ts[t] = s;
  __syncthreads();
  for (int o = 1; o < 256; o <<= 1) {
    int add = (t >= o) ? ts[t - o] : 0;
    __syncthreads();
    ts[t] += add;
    __syncthreads();
  }
  int excl = ts[t] - s;
  cur[2 * t] = excl;
  cur[2 * t + 1] = excl + c0;
  int n0 = b << 9;
  offs[n0 + 2 * t] = lo + excl;
  offs[n0 + 2 * t + 1] = lo + excl + c0;
  if (t == 255) bend[b] = lo + ts[255];
  __syncthreads();
  for (int e = lo + t; e < hi; e += 256) {
    int2 p = ep[e];
    int pos = atomicAdd(&cur[p.y & 511], 1);
    csr[lo + pos] = p.x;
  }
}

// ---------- compute ----------

// 16-deep bf16 neighbor gather (no BN): sum of h16[src]
__device__ __forceinline__ float gather_plain(
    const unsigned short* __restrict__ h16, const int* __restrict__ csr,
    int e0, int e1, int lane) {
  float acc = 0.f;
  int e = e0;
  for (; e + 16 <= e1; e += 16) {
    int s0 = csr[e], s1 = csr[e + 1], s2 = csr[e + 2], s3 = csr[e + 3];
    int s4 = csr[e + 4], s5 = csr[e + 5], s6 = csr[e + 6], s7 = csr[e + 7];
    int s8 = csr[e + 8], s9 = csr[e + 9], sa = csr[e + 10], sb = csr[e + 11];
    int sc = csr[e + 12], sd = csr[e + 13], se = csr[e + 14], sf = csr[e + 15];
    float a0 = bf2f(h16[(size_t)s0 * 64 + lane]);
    float a1 = bf2f(h16[(size_t)s1 * 64 + lane]);
    float a2 = bf2f(h16[(size_t)s2 * 64 + lane]);
    float a3 = bf2f(h16[(size_t)s3 * 64 + lane]);
    float a4 = bf2f(h16[(size_t)s4 * 64 + lane]);
    float a5 = bf2f(h16[(size_t)s5 * 64 + lane]);
    float a6 = bf2f(h16[(size_t)s6 * 64 + lane]);
    float a7 = bf2f(h16[(size_t)s7 * 64 + lane]);
    float a8 = bf2f(h16[(size_t)s8 * 64 + lane]);
    float a9 = bf2f(h16[(size_t)s9 * 64 + lane]);
    float aa = bf2f(h16[(size_t)sa * 64 + lane]);
    float ab = bf2f(h16[(size_t)sb * 64 + lane]);
    float ac = bf2f(h16[(size_t)sc * 64 + lane]);
    float ad = bf2f(h16[(size_t)sd * 64 + lane]);
    float ae = bf2f(h16[(size_t)se * 64 + lane]);
    float af = bf2f(h16[(size_t)sf * 64 + lane]);
    acc += (((a0 + a1) + (a2 + a3)) + ((a4 + a5) + (a6 + a7))) +
           (((a8 + a9) + (aa + ab)) + ((ac + ad) + (ae + af)));
  }
  for (; e + 4 <= e1; e += 4) {
    int s0 = csr[e], s1 = csr[e + 1], s2 = csr[e + 2], s3 = csr[e + 3];
    float a0 = bf2f(h16[(size_t)s0 * 64 + lane]);
    float a1 = bf2f(h16[(size_t)s1 * 64 + lane]);
    float a2 = bf2f(h16[(size_t)s2 * 64 + lane]);
    float a3 = bf2f(h16[(size_t)s3 * 64 + lane]);
    acc += (a0 + a1) + (a2 + a3);
  }
  for (; e < e1; e++) acc += bf2f(h16[(size_t)csr[e] * 64 + lane]);
  return acc;
}

// layer-0 aggregation: v[n] = x16[n] + sum x16[src]
__global__ __launch_bounds__(256) void k_agg(
    const unsigned short* __restrict__ h16, const int* __restrict__ offs,
    const int* __restrict__ bend, const int* __restrict__ csr,
    float* __restrict__ vout, int N) {
  int gid = blockIdx.x * blockDim.x + threadIdx.x;
  int wid = __builtin_amdgcn_readfirstlane(gid >> 6);
  int lane = threadIdx.x & 63;
  if (wid >= N) return;
  int e0 = offs[wid];
  int e1 = ((wid & 511) == 511) ? bend[wid >> 9] : offs[wid + 1];
  float acc = bf2f(h16[(size_t)wid * 64 + lane]) +
              gather_plain(h16, csr, e0, e1, lane);
  vout[(size_t)wid * 64 + lane] = acc;
}

// BN+ReLU aggregation (no head): v[n] = relu(z16[n]*A+B) + sum relu(z16[src]*A+B)
__global__ __launch_bounds__(256) void k_aggbn(
    const unsigned short* __restrict__ z16,
    const float* __restrict__ stats_in, const float* __restrict__ gv,
    const float* __restrict__ bev,
    const int* __restrict__ offs, const int* __restrict__ bend,
    const int* __restrict__ csr, float* __restrict__ vout, int N) {
  __shared__ float ABs[128];
  int tid = threadIdx.x;
  if (tid < 64) {
    float inv_n = 1.f / (float)N;
    float mu = stats_in[tid] * inv_n;
    float var = stats_in[64 + tid] * inv_n - mu * mu;
    float A = rsqrtf(var + BN_EPS) * gv[tid];
    ABs[tid] = A;
    ABs[64 + tid] = bev[tid] - mu * A;
  }
  __syncthreads();
  int gid = blockIdx.x * blockDim.x + tid;
  int wid = __builtin_amdgcn_readfirstlane(gid >> 6);
  int lane = tid & 63;
  if (wid >= N) return;
  float A = ABs[lane], B = ABs[64 + lane];
  float acc = fmaxf(bf2f(z16[(size_t)wid * 64 + lane]) * A + B, 0.f);
  int e0 = offs[wid];
  int e1 = ((wid & 511) == 511) ? bend[wid >> 9] : offs[wid + 1];
  int e = e0;
  for (; e + 16 <= e1; e += 16) {
    int s0 = csr[e], s1 = csr[e + 1], s2 = csr[e + 2], s3 = csr[e + 3];
    int s4 = csr[e + 4], s5 = csr[e + 5], s6 = csr[e + 6], s7 = csr[e + 7];
    int s8 = csr[e + 8], s9 = csr[e + 9], sa = csr[e + 10], sb = csr[e + 11];
    int sc = csr[e + 12], sd = csr[e + 13], se = csr[e + 14], sf = csr[e + 15];
    float a0 = bf2f(z16[(size_t)s0 * 64 + lane]);
    float a1 = bf2f(z16[(size_t)s1 * 64 + lane]);
    float a2 = bf2f(z16[(size_t)s2 * 64 + lane]);
    float a3 = bf2f(z16[(size_t)s3 * 64 + lane]);
    float a4 = bf2f(z16[(size_t)s4 * 64 + lane]);
    float a5 = bf2f(z16[(size_t)s5 * 64 + lane]);
    float a6 = bf2f(z16[(size_t)s6 * 64 + lane]);
    float a7 = bf2f(z16[(size_t)s7 * 64 + lane]);
    float a8 = bf2f(z16[(size_t)s8 * 64 + lane]);
    float a9 = bf2f(z16[(size_t)s9 * 64 + lane]);
    float aa = bf2f(z16[(size_t)sa * 64 + lane]);
    float ab = bf2f(z16[(size_t)sb * 64 + lane]);
    float ac = bf2f(z16[(size_t)sc * 64 + lane]);
    float ad = bf2f(z16[(size_t)sd * 64 + lane]);
    float ae = bf2f(z16[(size_t)se * 64 + lane]);
    float af = bf2f(z16[(size_t)sf * 64 + lane]);
    a0 = fmaxf(a0 * A + B, 0.f); a1 = fmaxf(a1 * A + B, 0.f);
    a2 = fmaxf(a2 * A + B, 0.f); a3 = fmaxf(a3 * A + B, 0.f);
    a4 = fmaxf(a4 * A + B, 0.f); a5 = fmaxf(a5 * A + B, 0.f);
    a6 = fmaxf(a6 * A + B, 0.f); a7 = fmaxf(a7 * A + B, 0.f);
    a8 = fmaxf(a8 * A + B, 0.f); a9 = fmaxf(a9 * A + B, 0.f);
    aa = fmaxf(aa * A + B, 0.f); ab = fmaxf(ab * A + B, 0.f);
    ac = fmaxf(ac * A + B, 0.f); ad = fmaxf(ad * A + B, 0.f);
    ae = fmaxf(ae * A + B, 0.f); af = fmaxf(af * A + B, 0.f);
    acc += (((a0 + a1) + (a2 + a3)) + ((a4 + a5) + (a6 + a7))) +
           (((a8 + a9) + (aa + ab)) + ((ac + ad) + (ae + af)));
  }
  for (; e + 4 <= e1; e += 4) {
    int s0 = csr[e], s1 = csr[e + 1], s2 = csr[e + 2], s3 = csr[e + 3];
    float a0 = bf2f(z16[(size_t)s0 * 64 + lane]);
    float a1 = bf2f(z16[(size_t)s1 * 64 + lane]);
    float a2 = bf2f(z16[(size_t)s2 * 64 + lane]);
    float a3 = bf2f(z16[(size_t)s3 * 64 + lane]);
    a0 = fmaxf(a0 * A + B, 0.f); a1 = fmaxf(a1 * A + B, 0.f);
    a2 = fmaxf(a2 * A + B, 0.f); a3 = fmaxf(a3 * A + B, 0.f);
    acc += (a0 + a1) + (a2 + a3);
  }
  for (; e < e1; e++) {
    float a = bf2f(z16[(size_t)csr[e] * 64 + lane]);
    acc += fmaxf(a * A + B, 0.f);
  }
  vout[(size_t)wid * 64 + lane] = acc;
}

// LDS-tiled GEMM, 128 rows/block, 4x8 thread tile.
//  dobn=1: AB from stats_in/gv/bev prologue; BN+ReLU on A staging.
//  z16out != nullptr: also emit bf16 shadow of output.
// Epilogue: column sum/sumsq -> atomicAdd stats_out[128].
__global__ __launch_bounds__(256) void k_gemm2(
    const float* __restrict__ vin, float* __restrict__ zout,
    unsigned short* __restrict__ z16out, const float* __restrict__ W,
    const float* __restrict__ stats_in, const float* __restrict__ gv,
    const float* __restrict__ bev, int dobn,
    float* __restrict__ stats_out, int N) {
  __shared__ float As[128 * 68];
  __shared__ float Ws[64 * 68];
  __shared__ float ABs[128];
  int tid = threadIdx.x;
  int n0 = blockIdx.x * 128;
  if (dobn) {
    if (tid < 64) {
      float inv_n = 1.f / (float)N;
      float mu = stats_in[tid] * inv_n;
      float var = stats_in[64 + tid] * inv_n - mu * mu;
      float A = rsqrtf(var + BN_EPS) * gv[tid];
      ABs[tid] = A;
      ABs[64 + tid] = bev[tid] - mu * A;
    }
    __syncthreads();
  }
#pragma unroll
  for (int i = 0; i < 4; i++) {
    int g = tid + i * 256;
    int r = g >> 4, q = g & 15;
    float4 t = *(const float4*)(W + r * 64 + 4 * q);
    int base = r * 68 + 4 * q;
    Ws[base] = t.x; Ws[base + 1] = t.y; Ws[base + 2] = t.z; Ws[base + 3] = t.w;
  }
#pragma unroll
  for (int i = 0; i < 8; i++) {
    int g = tid + i * 256;
    int r = g >> 4, q = g & 15;
    int rn = n0 + r;
    float4 t = make_float4(0.f, 0.f, 0.f, 0.f);
    if (rn < N) t = *(const float4*)(vin + (size_t)rn * 64 + 4 * q);
    if (dobn) {
      float4 a = *(const float4*)(ABs + 4 * q);
      float4 b = *(const float4*)(ABs + 64 + 4 * q);
      t.x = fmaxf(t.x * a.x + b.x, 0.f);
      t.y = fmaxf(t.y * a.y + b.y, 0.f);
      t.z = fmaxf(t.z * a.z + b.z, 0.f);
      t.w = fmaxf(t.w * a.w + b.w, 0.f);
    }
    int base = r * 68 + 4 * q;
    As[base] = t.x; As[base + 1] = t.y; As[base + 2] = t.z; As[base + 3] = t.w;
  }
  __syncthreads();
  int tr = tid >> 3, tc = tid & 7;
  int ra = tr * 4;
  float acc[4][8];
#pragma unroll
  for (int i = 0; i < 4; i++)
#pragma unroll
    for (int j = 0; j < 8; j++) acc[i][j] = 0.f;
#pragma unroll 4
  for (int k = 0; k < 64; k++) {
    float av[4];
#pragma unroll
    for (int i = 0; i < 4; i++) av[i] = As[(ra + i) * 68 + k];
    const float* wk = &Ws[k * 68 + tc * 8];
    float4 w0 = *(const float4*)wk;
    float4 w1 = *(const float4*)(wk + 4);
    float wv[8] = {w0.x, w0.y, w0.z, w0.w, w1.x, w1.y, w1.z, w1.w};
#pragma unroll
    for (int i = 0; i < 4; i++)
#pragma unroll
      for (int j = 0; j < 8; j++) acc[i][j] += av[i] * wv[j];
  }
#pragma unroll
  for (int i = 0; i < 4; i++) {
    int rn = n0 + ra + i;
    if (rn < N) {
      float* zr = zout + (size_t)rn * 64 + tc * 8;
      *(float4*)zr = make_float4(acc[i][0], acc[i][1], acc[i][2], acc[i][3]);
      *(float4*)(zr + 4) = make_float4(acc[i][4], acc[i][5], acc[i][6], acc[i][7]);
      if (z16out) {
        unsigned short* zs = z16out + (size_t)rn * 64 + tc * 8;
        *(ushort4*)zs = make_ushort4(f2bf(acc[i][0]), f2bf(acc[i][1]),
                                     f2bf(acc[i][2]), f2bf(acc[i][3]));
        *(ushort4*)(zs + 4) = make_ushort4(f2bf(acc[i][4]), f2bf(acc[i][5]),
                                           f2bf(acc[i][6]), f2bf(acc[i][7]));
      }
    }
  }
  float cs[8], cq[8];
#pragma unroll
  for (int j = 0; j < 8; j++) {
    float s = 0.f, q = 0.f;
#pragma unroll
    for (int i = 0; i < 4; i++) {
      s += acc[i][j];
      q += acc[i][j] * acc[i][j];
    }
    cs[j] = s;
    cq[j] = q;
  }
#pragma unroll
  for (int m = 8; m <= 32; m <<= 1) {
#pragma unroll
    for (int j = 0; j < 8; j++) {
      cs[j] += __shfl_xor(cs[j], m);
      cq[j] += __shfl_xor(cq[j], m);
    }
  }
  __syncthreads();
  int w = tid >> 6;
  if ((tid & 63) < 8) {
    int c = tc * 8;
#pragma unroll
    for (int j = 0; j < 8; j++) {
      Ws[w * 128 + c + j] = cs[j];
      Ws[w * 128 + 64 + c + j] = cq[j];
    }
  }
  __syncthreads();
  if (tid < 64) {
    float a = Ws[tid] + Ws[128 + tid] + Ws[256 + tid] + Ws[384 + tid];
    float b = Ws[64 + tid] + Ws[192 + tid] + Ws[320 + tid] + Ws[448 + tid];
    atomicAdd(&stats_out[tid], a);
    atomicAdd(&stats_out[64 + tid], b);
  }
}

// all three JK heads + log_softmax:
//  out[n] = lsm(logits[n] + sum_l relu(z2_l[n]*A_l+B_l) @ fcW_{l+1})
__global__ __launch_bounds__(256) void k_head_final3(
    const float* __restrict__ z0, const float* __restrict__ z1,
    const float* __restrict__ z2, const float* __restrict__ stats,
    const float* __restrict__ gbn, const float* __restrict__ bbn,
    const float* __restrict__ fcW, const float* __restrict__ logits,
    float* __restrict__ out, int N) {
  __shared__ float vs[256 * 17];
  __shared__ float ABs[3 * 128];
  int tid = threadIdx.x;
  if (tid < 64) {
    float inv_n = 1.f / (float)N;
#pragma unroll
    for (int l = 0; l < 3; l++) {
      const float* st = stats + (2 * l + 1) * 128;
      float mu = st[tid] * inv_n;
      float var = st[64 + tid] * inv_n - mu * mu;
      float A = rsqrtf(var + BN_EPS) * gbn[l * 64 + tid];
      ABs[l * 128 + tid] = A;
      ABs[l * 128 + 64 + tid] = bbn[l * 64 + tid] - mu * A;
    }
  }
  int n0 = blockIdx.x * 256;
  int n = n0 + tid;
  float acc[10];
#pragma unroll
  for (int c = 0; c < 10; c++) acc[c] = 0.f;
#pragma unroll 1
  for (int l = 0; l < 3; l++) {
    const float* z = (l == 0) ? z0 : (l == 1) ? z1 : z2;
    const float* fcWl = fcW + (l + 1) * 640;
    const float* AB = ABs + l * 128;
#pragma unroll 1
    for (int fb = 0; fb < 64; fb += 16) {
      __syncthreads();
#pragma unroll
      for (int g = 0; g < 4; g++) {
        int r = g * 64 + (tid >> 2);
        int q = tid & 3;
        int rn = n0 + r;
        float4 t = (rn < N) ? *(const float4*)(z + (size_t)rn * 64 + fb + 4 * q)
                            : make_float4(0.f, 0.f, 0.f, 0.f);
        int base = r * 17 + 4 * q;
        vs[base] = t.x;
        vs[base + 1] = t.y;
        vs[base + 2] = t.z;
        vs[base + 3] = t.w;
      }
      __syncthreads();
#pragma unroll
      for (int fc = 0; fc < 16; fc++) {
        int f = fb + fc;
        float val = fmaxf(vs[tid * 17 + fc] * AB[f] + AB[64 + f], 0.f);
        const float* wr = fcWl + f * 10;
#pragma unroll
        for (int c = 0; c < 10; c++) acc[c] += val * wr[c];
      }
    }
  }
  if (n < N) {
    const float* lr = logits + (size_t)n * 10;
    float v[10];
    float m = -INFINITY;
#pragma unroll
    for (int c = 0; c < 10; c++) {
      v[c] = lr[c] + acc[c];
      m = fmaxf(m, v[c]);
    }
    float s = 0.f;
#pragma unroll
    for (int c = 0; c < 10; c++) s += expf(v[c] - m);
    float l = logf(s) + m;
    float* orow = out + (size_t)n * 10;
#pragma unroll
    for (int c = 0; c < 10; c++) orow[c] = v[c] - l;
  }
}

extern "C" void kernel_launch(void* const* d_in, const int* in_sizes, int n_in,
                              void* d_out, int out_size, void* d_ws, size_t ws_size,
                              hipStream_t stream) {
  const float* x = (const float*)d_in[0];
  const int* ei = (const int*)d_in[1];
  const float* W1 = (const float*)d_in[2];
  const float* g1 = (const float*)d_in[4];
  const float* be1 = (const float*)d_in[5];
  const float* W2 = (const float*)d_in[6];
  const float* gbn = (const float*)d_in[8];
  const float* bbn = (const float*)d_in[9];
  const float* fcW = (const float*)d_in[10];
  const float* fcb = (const float*)d_in[11];
  float* out = (float*)d_out;

  const int N = in_sizes[0] / 64;
  const int E = in_sizes[1] / 2;
  const int* src = ei;
  const int* dst = ei + E;

  char* ws = (char*)d_ws;
  size_t off = 0;
  auto alloc = [&](size_t bytes) -> void* {
    void* p = ws + off;
    off = (off + bytes + 255) & ~(size_t)255;
    return p;
  };
  int* bcur = (int*)alloc(NBKT * 4);          // zeroed by memset node
  float* stats = (float*)alloc(6 * 128 * 4);  // zeroed by bucketsort blk 0
  int* offs = (int*)alloc((size_t)NBKT * 512 * 4);
  int* bend = (int*)alloc(NBKT * 4);
  int* csr = (int*)alloc((size_t)NBKT * BCAP * 4);
  float* zbuf = (float*)alloc((size_t)N * 64 * 4);  // z1 (GEMM1 out)
  float* z2a = (float*)alloc((size_t)N * 64 * 4);   // per-layer z2
  float* z2b = (float*)alloc((size_t)N * 64 * 4);
  float* z2c = (float*)alloc((size_t)N * 64 * 4);
  float* logits = (float*)alloc((size_t)N * 10 * 4);
  unsigned short* x16 = (unsigned short*)alloc((size_t)N * 64 * 2);
  unsigned short* z16 = (unsigned short*)alloc((size_t)N * 64 * 2);
  float* vbuf = (float*)alloc((size_t)N * 64 * 4);
  int2* ep = (int2*)alloc((size_t)NBKT * BCAP * 8);
  (void)ws_size;
  (void)n_in;
  (void)out_size;

  float* z2l[3] = {z2a, z2b, z2c};
  int nb = (N + 255) / 256;
  int gb = (N + 127) / 128;
  int ab = (N * 64 + 255) / 256;
  int nparts = (E + PCHUNK - 1) / PCHUNK;
  hipMemsetAsync(bcur, 0, NBKT * 4, stream);
  k_part_head<<<nparts + nb, 256, 0, stream>>>(src, dst, bcur, ep, E, nparts, x,
                                               fcW, fcb, logits, x16, N);
  k_bucketsort<<<NBKT, 256, 0, stream>>>(ep, bcur, offs, bend, csr, stats);

  for (int l = 0; l < 3; l++) {
    float* st1 = stats + (2 * l) * 128;
    float* st2 = stats + (2 * l + 1) * 128;
    if (l == 0) {
      k_agg<<<ab, 256, 0, stream>>>(x16, offs, bend, csr, vbuf, N);
    } else {
      float* st2p = stats + (2 * (l - 1) + 1) * 128;
      k_aggbn<<<ab, 256, 0, stream>>>(z16, st2p, gbn + (l - 1) * 64,
                                      bbn + (l - 1) * 64, offs, bend, csr,
                                      vbuf, N);
    }
    k_gemm2<<<gb, 256, 0, stream>>>(vbuf, zbuf, nullptr, W1 + l * 4096, nullptr,
                                    nullptr, nullptr, 0, st1, N);
    unsigned short* zs = (l < 2) ? z16 : nullptr;
    k_gemm2<<<gb, 256, 0, stream>>>(zbuf, z2l[l], zs, W2 + l * 4096, st1,
                                    g1 + l * 64, be1 + l * 64, 1, st2, N);
  }
  k_head_final3<<<nb, 256, 0, stream>>>(z2a, z2b, z2c, stats, gbn, bbn, fcW,
                                        logits, out, N);
}

// Round 13
// 530.504 us; speedup vs baseline: 10.7684x; 1.0310x over previous
//
#include <hip/hip_runtime.h>
#include <math.h>

// GIN: N=100000 nodes, E=1600000 edges, F=D=64, L=3 layers, C=10 classes.
// R13: all intermediate N*64 buffers -> bf16 (~270MB less HBM traffic):
//   - agg/aggbn write v16 (bf16); GEMM1 stages A from bf16.
//   - GEMM1 writes z1 as bf16; GEMM2 stages from it (BN is affine; stats
//     stay exact fp32 from GEMM epilogue accumulators).
//   - fp32 z2 deleted: GEMM2 writes only per-layer bf16 z16_l; aggbn and
//     head_final3 read bf16. Launch structure unchanged (13 nodes;
//     R8/R9 showed persistent-kernel barriers thrash L1 device-wide).

#define BN_EPS 1e-5f
#define NBKT 256     // dst buckets (dst>>9)
#define BCAP 12288   // per-bucket edge capacity (mean 8163, +45 sigma)
#define PCHUNK 4096  // edges per partition block

__device__ __forceinline__ float bf2f(unsigned short u) {
  return __uint_as_float(((unsigned int)u) << 16);
}
__device__ __forceinline__ unsigned short f2bf(float x) {  // RNE
  unsigned int b = __float_as_uint(x);
  return (unsigned short)((b + 0x7FFFu + ((b >> 16) & 1u)) >> 16);
}

// ---------- CSR build ----------

// combined dispatch: blocks [0,nparts) partition edges into fixed-capacity
// dst-buckets (direct atomicAdd on bcur); rest do head_init (+x16 shadow).
__global__ __launch_bounds__(256) void k_part_head(
    const int* __restrict__ src, const int* __restrict__ dst,
    int* __restrict__ bcur, int2* __restrict__ ep, int E, int nparts,
    const float* __restrict__ x, const float* __restrict__ fcW0,
    const float* __restrict__ fcb, float* __restrict__ logits,
    unsigned short* __restrict__ x16, int N) {
  __shared__ char smem[256 * 17 * 4];
  int tid = threadIdx.x;
  if ((int)blockIdx.x < nparts) {
    int* lh = (int*)smem;
    int* lbase = lh + NBKT;
    int* lcur = lh + 2 * NBKT;
    int base = blockIdx.x * PCHUNK;
    int end = min(base + PCHUNK, E);
    lh[tid] = 0;
    lcur[tid] = 0;
    __syncthreads();
    for (int e = base + tid; e < end; e += 256) atomicAdd(&lh[dst[e] >> 9], 1);
    __syncthreads();
    int c = lh[tid];
    lbase[tid] = c ? (tid * BCAP + atomicAdd(&bcur[tid], c)) : 0;
    __syncthreads();
    for (int e = base + tid; e < end; e += 256) {
      int d = dst[e];
      int b = d >> 9;
      int r = atomicAdd(&lcur[b], 1);
      ep[lbase[b] + r] = make_int2(src[e], d);
    }
  } else {
    float* vs = (float*)smem;
    int n0 = (blockIdx.x - nparts) * 256;
    int n = n0 + tid;
    float acc[10];
#pragma unroll
    for (int c = 0; c < 10; c++) acc[c] = 0.f;
#pragma unroll 1
    for (int fb = 0; fb < 64; fb += 16) {
      __syncthreads();
#pragma unroll
      for (int g = 0; g < 4; g++) {
        int r = g * 64 + (tid >> 2);
        int q = tid & 3;
        int rn = n0 + r;
        float4 t = make_float4(0.f, 0.f, 0.f, 0.f);
        if (rn < N) {
          t = *(const float4*)(x + (size_t)rn * 64 + fb + 4 * q);
          *(ushort4*)(x16 + (size_t)rn * 64 + fb + 4 * q) =
              make_ushort4(f2bf(t.x), f2bf(t.y), f2bf(t.z), f2bf(t.w));
        }
        int base = r * 17 + 4 * q;
        vs[base] = t.x;
        vs[base + 1] = t.y;
        vs[base + 2] = t.z;
        vs[base + 3] = t.w;
      }
      __syncthreads();
      for (int fc = 0; fc < 16; fc++) {
        int f = fb + fc;
        float vf = vs[tid * 17 + fc];
        const float* wr = fcW0 + f * 10;
#pragma unroll
        for (int c = 0; c < 10; c++) acc[c] += vf * wr[c];
      }
    }
    if (n < N) {
      float* lr = logits + (size_t)n * 10;
#pragma unroll
      for (int c = 0; c < 10; c++)
        lr[c] = acc[c] + (fcb[c] + fcb[10 + c] + fcb[20 + c] + fcb[30 + c]);
    }
  }
}

// per-bucket LDS counting sort. Emits offs, bend[b], csr. Blk 0 zeroes stats.
__global__ __launch_bounds__(256) void k_bucketsort(
    const int2* __restrict__ ep, const int* __restrict__ bcur,
    int* __restrict__ offs, int* __restrict__ bend, int* __restrict__ csr,
    float* __restrict__ stats) {
  __shared__ int cnt[512];
  __shared__ int ts[256];
  __shared__ int cur[512];
  int t = threadIdx.x;
  int b = blockIdx.x;
  if (b == 0) {
    for (int i = t; i < 768; i += 256) stats[i] = 0.f;
  }
  int lo = b * BCAP;
  int hi = lo + bcur[b];
  cnt[t] = 0;
  cnt[t + 256] = 0;
  __syncthreads();
  for (int e = lo + t; e < hi; e += 256) atomicAdd(&cnt[ep[e].y & 511], 1);
  __syncthreads();
  int c0 = cnt[2 * t], c1 = cnt[2 * t + 1];
  int s = c0 + c1;
  ts[t] = s;
  __syncthreads();
  for (int o = 1; o < 256; o <<= 1) {
    int add = (t >= o) ? ts[t - o] : 0;
    __syncthreads();
    ts[t] += add;
    __syncthreads();
  }
  int excl = ts[t] - s;
  cur[2 * t] = excl;
  cur[2 * t + 1] = excl + c0;
  int n0 = b << 9;
  offs[n0 + 2 * t] = lo + excl;
  offs[n0 + 2 * t + 1] = lo + excl + c0;
  if (t == 255) bend[b] = lo + ts[255];
  __syncthreads();
  for (int e = lo + t; e < hi; e += 256) {
    int2 p = ep[e];
    int pos = atomicAdd(&cur[p.y & 511], 1);
    csr[lo + pos] = p.x;
  }
}

// ---------- compute ----------

// 16-deep bf16 neighbor gather (no BN): sum of h16[src]
__device__ __forceinline__ float gather_plain(
    const unsigned short* __restrict__ h16, const int* __restrict__ csr,
    int e0, int e1, int lane) {
  float acc = 0.f;
  int e = e0;
  for (; e + 16 <= e1; e += 16) {
    int s0 = csr[e], s1 = csr[e + 1], s2 = csr[e + 2], s3 = csr[e + 3];
    int s4 = csr[e + 4], s5 = csr[e + 5], s6 = csr[e + 6], s7 = csr[e + 7];
    int s8 = csr[e + 8], s9 = csr[e + 9], sa = csr[e + 10], sb = csr[e + 11];
    int sc = csr[e + 12], sd = csr[e + 13], se = csr[e + 14], sf = csr[e + 15];
    float a0 = bf2f(h16[(size_t)s0 * 64 + lane]);
    float a1 = bf2f(h16[(size_t)s1 * 64 + lane]);
    float a2 = bf2f(h16[(size_t)s2 * 64 + lane]);
    float a3 = bf2f(h16[(size_t)s3 * 64 + lane]);
    float a4 = bf2f(h16[(size_t)s4 * 64 + lane]);
    float a5 = bf2f(h16[(size_t)s5 * 64 + lane]);
    float a6 = bf2f(h16[(size_t)s6 * 64 + lane]);
    float a7 = bf2f(h16[(size_t)s7 * 64 + lane]);
    float a8 = bf2f(h16[(size_t)s8 * 64 + lane]);
    float a9 = bf2f(h16[(size_t)s9 * 64 + lane]);
    float aa = bf2f(h16[(size_t)sa * 64 + lane]);
    float ab = bf2f(h16[(size_t)sb * 64 + lane]);
    float ac = bf2f(h16[(size_t)sc * 64 + lane]);
    float ad = bf2f(h16[(size_t)sd * 64 + lane]);
    float ae = bf2f(h16[(size_t)se * 64 + lane]);
    float af = bf2f(h16[(size_t)sf * 64 + lane]);
    acc += (((a0 + a1) + (a2 + a3)) + ((a4 + a5) + (a6 + a7))) +
           (((a8 + a9) + (aa + ab)) + ((ac + ad) + (ae + af)));
  }
  for (; e + 4 <= e1; e += 4) {
    int s0 = csr[e], s1 = csr[e + 1], s2 = csr[e + 2], s3 = csr[e + 3];
    float a0 = bf2f(h16[(size_t)s0 * 64 + lane]);
    float a1 = bf2f(h16[(size_t)s1 * 64 + lane]);
    float a2 = bf2f(h16[(size_t)s2 * 64 + lane]);
    float a3 = bf2f(h16[(size_t)s3 * 64 + lane]);
    acc += (a0 + a1) + (a2 + a3);
  }
  for (; e < e1; e++) acc += bf2f(h16[(size_t)csr[e] * 64 + lane]);
  return acc;
}

// layer-0 aggregation: v16[n] = bf16(x16[n] + sum x16[src])
__global__ __launch_bounds__(256) void k_agg(
    const unsigned short* __restrict__ h16, const int* __restrict__ offs,
    const int* __restrict__ bend, const int* __restrict__ csr,
    unsigned short* __restrict__ vout, int N) {
  int gid = blockIdx.x * blockDim.x + threadIdx.x;
  int wid = __builtin_amdgcn_readfirstlane(gid >> 6);
  int lane = threadIdx.x & 63;
  if (wid >= N) return;
  int e0 = offs[wid];
  int e1 = ((wid & 511) == 511) ? bend[wid >> 9] : offs[wid + 1];
  float acc = bf2f(h16[(size_t)wid * 64 + lane]) +
              gather_plain(h16, csr, e0, e1, lane);
  vout[(size_t)wid * 64 + lane] = f2bf(acc);
}

// BN+ReLU aggregation: v16[n] = bf16(relu(z16[n]*A+B) + sum relu(z16[src]*A+B))
__global__ __launch_bounds__(256) void k_aggbn(
    const unsigned short* __restrict__ z16,
    const float* __restrict__ stats_in, const float* __restrict__ gv,
    const float* __restrict__ bev,
    const int* __restrict__ offs, const int* __restrict__ bend,
    const int* __restrict__ csr, unsigned short* __restrict__ vout, int N) {
  __shared__ float ABs[128];
  int tid = threadIdx.x;
  if (tid < 64) {
    float inv_n = 1.f / (float)N;
    float mu = stats_in[tid] * inv_n;
    float var = stats_in[64 + tid] * inv_n - mu * mu;
    float A = rsqrtf(var + BN_EPS) * gv[tid];
    ABs[tid] = A;
    ABs[64 + tid] = bev[tid] - mu * A;
  }
  __syncthreads();
  int gid = blockIdx.x * blockDim.x + tid;
  int wid = __builtin_amdgcn_readfirstlane(gid >> 6);
  int lane = tid & 63;
  if (wid >= N) return;
  float A = ABs[lane], B = ABs[64 + lane];
  float acc = fmaxf(bf2f(z16[(size_t)wid * 64 + lane]) * A + B, 0.f);
  int e0 = offs[wid];
  int e1 = ((wid & 511) == 511) ? bend[wid >> 9] : offs[wid + 1];
  int e = e0;
  for (; e + 16 <= e1; e += 16) {
    int s0 = csr[e], s1 = csr[e + 1], s2 = csr[e + 2], s3 = csr[e + 3];
    int s4 = csr[e + 4], s5 = csr[e + 5], s6 = csr[e + 6], s7 = csr[e + 7];
    int s8 = csr[e + 8], s9 = csr[e + 9], sa = csr[e + 10], sb = csr[e + 11];
    int sc = csr[e + 12], sd = csr[e + 13], se = csr[e + 14], sf = csr[e + 15];
    float a0 = bf2f(z16[(size_t)s0 * 64 + lane]);
    float a1 = bf2f(z16[(size_t)s1 * 64 + lane]);
    float a2 = bf2f(z16[(size_t)s2 * 64 + lane]);
    float a3 = bf2f(z16[(size_t)s3 * 64 + lane]);
    float a4 = bf2f(z16[(size_t)s4 * 64 + lane]);
    float a5 = bf2f(z16[(size_t)s5 * 64 + lane]);
    float a6 = bf2f(z16[(size_t)s6 * 64 + lane]);
    float a7 = bf2f(z16[(size_t)s7 * 64 + lane]);
    float a8 = bf2f(z16[(size_t)s8 * 64 + lane]);
    float a9 = bf2f(z16[(size_t)s9 * 64 + lane]);
    float aa = bf2f(z16[(size_t)sa * 64 + lane]);
    float ab = bf2f(z16[(size_t)sb * 64 + lane]);
    float ac = bf2f(z16[(size_t)sc * 64 + lane]);
    float ad = bf2f(z16[(size_t)sd * 64 + lane]);
    float ae = bf2f(z16[(size_t)se * 64 + lane]);
    float af = bf2f(z16[(size_t)sf * 64 + lane]);
    a0 = fmaxf(a0 * A + B, 0.f); a1 = fmaxf(a1 * A + B, 0.f);
    a2 = fmaxf(a2 * A + B, 0.f); a3 = fmaxf(a3 * A + B, 0.f);
    a4 = fmaxf(a4 * A + B, 0.f); a5 = fmaxf(a5 * A + B, 0.f);
    a6 = fmaxf(a6 * A + B, 0.f); a7 = fmaxf(a7 * A + B, 0.f);
    a8 = fmaxf(a8 * A + B, 0.f); a9 = fmaxf(a9 * A + B, 0.f);
    aa = fmaxf(aa * A + B, 0.f); ab = fmaxf(ab * A + B, 0.f);
    ac = fmaxf(ac * A + B, 0.f); ad = fmaxf(ad * A + B, 0.f);
    ae = fmaxf(ae * A + B, 0.f); af = fmaxf(af * A + B, 0.f);
    acc += (((a0 + a1) + (a2 + a3)) + ((a4 + a5) + (a6 + a7))) +
           (((a8 + a9) + (aa + ab)) + ((ac + ad) + (ae + af)));
  }
  for (; e + 4 <= e1; e += 4) {
    int s0 = csr[e], s1 = csr[e + 1], s2 = csr[e + 2], s3 = csr[e + 3];
    float a0 = bf2f(z16[(size_t)s0 * 64 + lane]);
    float a1 = bf2f(z16[(size_t)s1 * 64 + lane]);
    float a2 = bf2f(z16[(size_t)s2 * 64 + lane]);
    float a3 = bf2f(z16[(size_t)s3 * 64 + lane]);
    a0 = fmaxf(a0 * A + B, 0.f); a1 = fmaxf(a1 * A + B, 0.f);
    a2 = fmaxf(a2 * A + B, 0.f); a3 = fmaxf(a3 * A + B, 0.f);
    acc += (a0 + a1) + (a2 + a3);
  }
  for (; e < e1; e++) {
    float a = bf2f(z16[(size_t)csr[e] * 64 + lane]);
    acc += fmaxf(a * A + B, 0.f);
  }
  vout[(size_t)wid * 64 + lane] = f2bf(acc);
}

// LDS-tiled GEMM, 128 rows/block, 4x8 thread tile. bf16 in -> bf16 out.
//  dobn=1: AB from stats_in/gv/bev prologue; BN+ReLU on A staging.
// Epilogue: column sum/sumsq (fp32 accumulators) -> atomicAdd stats_out[128].
__global__ __launch_bounds__(256) void k_gemm2(
    const unsigned short* __restrict__ vin, unsigned short* __restrict__ zout,
    const float* __restrict__ W,
    const float* __restrict__ stats_in, const float* __restrict__ gv,
    const float* __restrict__ bev, int dobn,
    float* __restrict__ stats_out, int N) {
  __shared__ float As[128 * 68];
  __shared__ float Ws[64 * 68];
  __shared__ float ABs[128];
  int tid = threadIdx.x;
  int n0 = blockIdx.x * 128;
  if (dobn) {
    if (tid < 64) {
      float inv_n = 1.f / (float)N;
      float mu = stats_in[tid] * inv_n;
      float var = stats_in[64 + tid] * inv_n - mu * mu;
      float A = rsqrtf(var + BN_EPS) * gv[tid];
      ABs[tid] = A;
      ABs[64 + tid] = bev[tid] - mu * A;
    }
    __syncthreads();
  }
#pragma unroll
  for (int i = 0; i < 4; i++) {
    int g = tid + i * 256;
    int r = g >> 4, q = g & 15;
    float4 t = *(const float4*)(W + r * 64 + 4 * q);
    int base = r * 68 + 4 * q;
    Ws[base] = t.x; Ws[base + 1] = t.y; Ws[base + 2] = t.z; Ws[base + 3] = t.w;
  }
#pragma unroll
  for (int i = 0; i < 8; i++) {
    int g = tid + i * 256;
    int r = g >> 4, q = g & 15;
    int rn = n0 + r;
    float4 t = make_float4(0.f, 0.f, 0.f, 0.f);
    if (rn < N) {
      ushort4 u = *(const ushort4*)(vin + (size_t)rn * 64 + 4 * q);
      t = make_float4(bf2f(u.x), bf2f(u.y), bf2f(u.z), bf2f(u.w));
    }
    if (dobn) {
      float4 a = *(const float4*)(ABs + 4 * q);
      float4 b = *(const float4*)(ABs + 64 + 4 * q);
      t.x = fmaxf(t.x * a.x + b.x, 0.f);
      t.y = fmaxf(t.y * a.y + b.y, 0.f);
      t.z = fmaxf(t.z * a.z + b.z, 0.f);
      t.w = fmaxf(t.w * a.w + b.w, 0.f);
    }
    int base = r * 68 + 4 * q;
    As[base] = t.x; As[base + 1] = t.y; As[base + 2] = t.z; As[base + 3] = t.w;
  }
  __syncthreads();
  int tr = tid >> 3, tc = tid & 7;
  int ra = tr * 4;
  float acc[4][8];
#pragma unroll
  for (int i = 0; i < 4; i++)
#pragma unroll
    for (int j = 0; j < 8; j++) acc[i][j] = 0.f;
#pragma unroll 4
  for (int k = 0; k < 64; k++) {
    float av[4];
#pragma unroll
    for (int i = 0; i < 4; i++) av[i] = As[(ra + i) * 68 + k];
    const float* wk = &Ws[k * 68 + tc * 8];
    float4 w0 = *(const float4*)wk;
    float4 w1 = *(const float4*)(wk + 4);
    float wv[8] = {w0.x, w0.y, w0.z, w0.w, w1.x, w1.y, w1.z, w1.w};
#pragma unroll
    for (int i = 0; i < 4; i++)
#pragma unroll
      for (int j = 0; j < 8; j++) acc[i][j] += av[i] * wv[j];
  }
#pragma unroll
  for (int i = 0; i < 4; i++) {
    int rn = n0 + ra + i;
    if (rn < N) {
      unsigned short* zs = zout + (size_t)rn * 64 + tc * 8;
      *(ushort4*)zs = make_ushort4(f2bf(acc[i][0]), f2bf(acc[i][1]),
                                   f2bf(acc[i][2]), f2bf(acc[i][3]));
      *(ushort4*)(zs + 4) = make_ushort4(f2bf(acc[i][4]), f2bf(acc[i][5]),
                                         f2bf(acc[i][6]), f2bf(acc[i][7]));
    }
  }
  float cs[8], cq[8];
#pragma unroll
  for (int j = 0; j < 8; j++) {
    float s = 0.f, q = 0.f;
#pragma unroll
    for (int i = 0; i < 4; i++) {
      s += acc[i][j];
      q += acc[i][j] * acc[i][j];
    }
    cs[j] = s;
    cq[j] = q;
  }
#pragma unroll
  for (int m = 8; m <= 32; m <<= 1) {
#pragma unroll
    for (int j = 0; j < 8; j++) {
      cs[j] += __shfl_xor(cs[j], m);
      cq[j] += __shfl_xor(cq[j], m);
    }
  }
  __syncthreads();
  int w = tid >> 6;
  if ((tid & 63) < 8) {
    int c = tc * 8;
#pragma unroll
    for (int j = 0; j < 8; j++) {
      Ws[w * 128 + c + j] = cs[j];
      Ws[w * 128 + 64 + c + j] = cq[j];
    }
  }
  __syncthreads();
  if (tid < 64) {
    float a = Ws[tid] + Ws[128 + tid] + Ws[256 + tid] + Ws[384 + tid];
    float b = Ws[64 + tid] + Ws[192 + tid] + Ws[320 + tid] + Ws[448 + tid];
    atomicAdd(&stats_out[tid], a);
    atomicAdd(&stats_out[64 + tid], b);
  }
}

// all three JK heads + log_softmax (bf16 z2 shadows):
//  out[n] = lsm(logits[n] + sum_l relu(z16_l[n]*A_l+B_l) @ fcW_{l+1})
__global__ __launch_bounds__(256) void k_head_final3(
    const unsigned short* __restrict__ z0, const unsigned short* __restrict__ z1,
    const unsigned short* __restrict__ z2, const float* __restrict__ stats,
    const float* __restrict__ gbn, const float* __restrict__ bbn,
    const float* __restrict__ fcW, const float* __restrict__ logits,
    float* __restrict__ out, int N) {
  __shared__ float vs[256 * 17];
  __shared__ float ABs[3 * 128];
  int tid = threadIdx.x;
  if (tid < 64) {
    float inv_n = 1.f / (float)N;
#pragma unroll
    for (int l = 0; l < 3; l++) {
      const float* st = stats + (2 * l + 1) * 128;
      float mu = st[tid] * inv_n;
      float var = st[64 + tid] * inv_n - mu * mu;
      float A = rsqrtf(var + BN_EPS) * gbn[l * 64 + tid];
      ABs[l * 128 + tid] = A;
      ABs[l * 128 + 64 + tid] = bbn[l * 64 + tid] - mu * A;
    }
  }
  int n0 = blockIdx.x * 256;
  int n = n0 + tid;
  float acc[10];
#pragma unroll
  for (int c = 0; c < 10; c++) acc[c] = 0.f;
#pragma unroll 1
  for (int l = 0; l < 3; l++) {
    const unsigned short* z = (l == 0) ? z0 : (l == 1) ? z1 : z2;
    const float* fcWl = fcW + (l + 1) * 640;
    const float* AB = ABs + l * 128;
#pragma unroll 1
    for (int fb = 0; fb < 64; fb += 16) {
      __syncthreads();
#pragma unroll
      for (int g = 0; g < 4; g++) {
        int r = g * 64 + (tid >> 2);
        int q = tid & 3;
        int rn = n0 + r;
        float4 t = make_float4(0.f, 0.f, 0.f, 0.f);
        if (rn < N) {
          ushort4 u = *(const ushort4*)(z + (size_t)rn * 64 + fb + 4 * q);
          t = make_float4(bf2f(u.x), bf2f(u.y), bf2f(u.z), bf2f(u.w));
        }
        int base = r * 17 + 4 * q;
        vs[base] = t.x;
        vs[base + 1] = t.y;
        vs[base + 2] = t.z;
        vs[base + 3] = t.w;
      }
      __syncthreads();
#pragma unroll
      for (int fc = 0; fc < 16; fc++) {
        int f = fb + fc;
        float val = fmaxf(vs[tid * 17 + fc] * AB[f] + AB[64 + f], 0.f);
        const float* wr = fcWl + f * 10;
#pragma unroll
        for (int c = 0; c < 10; c++) acc[c] += val * wr[c];
      }
    }
  }
  if (n < N) {
    const float* lr = logits + (size_t)n * 10;
    float v[10];
    float m = -INFINITY;
#pragma unroll
    for (int c = 0; c < 10; c++) {
      v[c] = lr[c] + acc[c];
      m = fmaxf(m, v[c]);
    }
    float s = 0.f;
#pragma unroll
    for (int c = 0; c < 10; c++) s += expf(v[c] - m);
    float l = logf(s) + m;
    float* orow = out + (size_t)n * 10;
#pragma unroll
    for (int c = 0; c < 10; c++) orow[c] = v[c] - l;
  }
}

extern "C" void kernel_launch(void* const* d_in, const int* in_sizes, int n_in,
                              void* d_out, int out_size, void* d_ws, size_t ws_size,
                              hipStream_t stream) {
  const float* x = (const float*)d_in[0];
  const int* ei = (const int*)d_in[1];
  const float* W1 = (const float*)d_in[2];
  const float* g1 = (const float*)d_in[4];
  const float* be1 = (const float*)d_in[5];
  const float* W2 = (const float*)d_in[6];
  const float* gbn = (const float*)d_in[8];
  const float* bbn = (const float*)d_in[9];
  const float* fcW = (const float*)d_in[10];
  const float* fcb = (const float*)d_in[11];
  float* out = (float*)d_out;

  const int N = in_sizes[0] / 64;
  const int E = in_sizes[1] / 2;
  const int* src = ei;
  const int* dst = ei + E;

  char* ws = (char*)d_ws;
  size_t off = 0;
  auto alloc = [&](size_t bytes) -> void* {
    void* p = ws + off;
    off = (off + bytes + 255) & ~(size_t)255;
    return p;
  };
  int* bcur = (int*)alloc(NBKT * 4);          // zeroed by memset node
  float* stats = (float*)alloc(6 * 128 * 4);  // zeroed by bucketsort blk 0
  int* offs = (int*)alloc((size_t)NBKT * 512 * 4);
  int* bend = (int*)alloc(NBKT * 4);
  int* csr = (int*)alloc((size_t)NBKT * BCAP * 4);
  float* logits = (float*)alloc((size_t)N * 10 * 4);
  unsigned short* x16 = (unsigned short*)alloc((size_t)N * 64 * 2);
  unsigned short* v16 = (unsigned short*)alloc((size_t)N * 64 * 2);
  unsigned short* z1_16 = (unsigned short*)alloc((size_t)N * 64 * 2);
  unsigned short* z16a = (unsigned short*)alloc((size_t)N * 64 * 2);
  unsigned short* z16b = (unsigned short*)alloc((size_t)N * 64 * 2);
  unsigned short* z16c = (unsigned short*)alloc((size_t)N * 64 * 2);
  int2* ep = (int2*)alloc((size_t)NBKT * BCAP * 8);
  (void)ws_size;
  (void)n_in;
  (void)out_size;

  unsigned short* z16l[3] = {z16a, z16b, z16c};
  int nb = (N + 255) / 256;
  int gb = (N + 127) / 128;
  int ab = (N * 64 + 255) / 256;
  int nparts = (E + PCHUNK - 1) / PCHUNK;
  hipMemsetAsync(bcur, 0, NBKT * 4, stream);
  k_part_head<<<nparts + nb, 256, 0, stream>>>(src, dst, bcur, ep, E, nparts, x,
                                               fcW, fcb, logits, x16, N);
  k_bucketsort<<<NBKT, 256, 0, stream>>>(ep, bcur, offs, bend, csr, stats);

  for (int l = 0; l < 3; l++) {
    float* st1 = stats + (2 * l) * 128;
    float* st2 = stats + (2 * l + 1) * 128;
    if (l == 0) {
      k_agg<<<ab, 256, 0, stream>>>(x16, offs, bend, csr, v16, N);
    } else {
      float* st2p = stats + (2 * (l - 1) + 1) * 128;
      k_aggbn<<<ab, 256, 0, stream>>>(z16l[l - 1], st2p, gbn + (l - 1) * 64,
                                      bbn + (l - 1) * 64, offs, bend, csr,
                                      v16, N);
    }
    k_gemm2<<<gb, 256, 0, stream>>>(v16, z1_16, W1 + l * 4096, nullptr, nullptr,
                                    nullptr, 0, st1, N);
    k_gemm2<<<gb, 256, 0, stream>>>(z1_16, z16l[l], W2 + l * 4096, st1,
                                    g1 + l * 64, be1 + l * 64, 1, st2, N);
  }
  k_head_final3<<<nb, 256, 0, stream>>>(z16a, z16b, z16c, stats, gbn, bbn, fcW,
                                        logits, out, N);
}